// Round 1
// baseline (3277.922 us; speedup 1.0000x reference)
//
#include <hip/hip_runtime.h>
#include <cstdint>
#include <cstddef>

#define B_  64
#define NC_ 32
#define NL_ 64
#define E_  256
#define H_  256

// ---------------- Threefry-2x32, 20 rounds (JAX-compatible) ----------------
__device__ __forceinline__ void tf2x32(unsigned k0, unsigned k1,
                                       unsigned c0, unsigned c1,
                                       unsigned &o0, unsigned &o1) {
  unsigned ks2 = k0 ^ k1 ^ 0x1BD11BDAu;
  unsigned x0 = c0 + k0, x1 = c1 + k1;
#define TFR(r) { x0 += x1; x1 = (x1 << r) | (x1 >> (32 - r)); x1 ^= x0; }
  TFR(13) TFR(15) TFR(26) TFR(6)   x0 += k1;  x1 += ks2 + 1u;
  TFR(17) TFR(29) TFR(16) TFR(24)  x0 += ks2; x1 += k0 + 2u;
  TFR(13) TFR(15) TFR(26) TFR(6)   x0 += k0;  x1 += k1 + 3u;
  TFR(17) TFR(29) TFR(16) TFR(24)  x0 += k1;  x1 += ks2 + 4u;
  TFR(13) TFR(15) TFR(26) TFR(6)   x0 += ks2; x1 += k0 + 5u;
#undef TFR
  o0 = x0; o1 = x1;
}

// partitionable random_bits (32-bit): bits = x0 ^ x1 of threefry(key, (0, flat))
__device__ __forceinline__ float gumbel_bits(unsigned k0, unsigned k1, unsigned flat) {
  unsigned a, b;
  tf2x32(k0, k1, 0u, flat, a, b);
  unsigned bits = a ^ b;
  float f = __uint_as_float(0x3F800000u | (bits >> 9)) - 1.0f;
  f = fmaxf(f, 1.17549435e-38f);
  return -logf(-logf(f));
}

__device__ __forceinline__ float ftanh(float x) {
  // tanh(x) = 1 - 2/(exp(2x)+1); accurate to ~1e-7, handles +-inf saturation
  return 1.0f - 2.0f / (__expf(2.0f * x) + 1.0f);
}

// ---------------- K0: keys + init vectors ----------------
__global__ __launch_bounds__(256) void k0_kernel(
    const float* __restrict__ init_w, const float* __restrict__ Wv,
    const float* __restrict__ hWq,
    const float* __restrict__ low_init_w, const float* __restrict__ lWv,
    const float* __restrict__ lWq,
    unsigned* __restrict__ hkeys, unsigned* __restrict__ lkeys,
    float* __restrict__ g0h, float* __restrict__ g0l) {
  int tid = threadIdx.x;
  __shared__ float s_iwv[E_], s_liwv[E_];
  if (tid < 32) {
    unsigned a, b;
    tf2x32(0u, 42u, 0u, (unsigned)tid, a, b);   // split(key(42), 32)[tid]
    hkeys[2*tid] = a; hkeys[2*tid+1] = b;
    tf2x32(0u, 7u, 0u, (unsigned)tid, a, b);    // split(key(7), 32)[tid]
    lkeys[2*tid] = a; lkeys[2*tid+1] = b;
  }
  {
    float a = 0.f, a2 = 0.f;
    for (int k = 0; k < 2*E_; ++k) {
      a  = fmaf(init_w[k],     Wv[(size_t)k*E_ + tid], a);
      a2 = fmaf(low_init_w[k], lWv[(size_t)k*E_ + tid], a2);
    }
    s_iwv[tid] = a; s_liwv[tid] = a2;
  }
  __syncthreads();
  {
    float a = 0.f, a2 = 0.f;
    for (int e = 0; e < E_; ++e) {
      a  = fmaf(s_iwv[e],  hWq[(size_t)e*H_ + tid], a);
      a2 = fmaf(s_liwv[e], lWq[(size_t)e*H_ + tid], a2);
    }
    g0h[tid] = a; g0l[tid] = a2;
  }
}

// ---------------- means over middle dim ----------------
__global__ __launch_bounds__(256) void k_mean(const float* __restrict__ in,
                                              float* __restrict__ out, int G) {
  int row = blockIdx.x, h = threadIdx.x;
  const float* p = in + (size_t)row * G * E_ + h;
  float a = 0.f;
  for (int g = 0; g < G; ++g) a += p[(size_t)g * E_];
  out[(size_t)row * E_ + h] = a * (1.0f / G);
}

// ---------------- generic small GEMM: C = (A .+ avec) @ W + bias ----------------
// A: M x K (lda), W: K x N (ldw=N), C: M x N. Block: 256 thr, tile 16M x 64N.
__global__ __launch_bounds__(256) void k_gemm(
    const float* __restrict__ A, int lda, const float* __restrict__ avec,
    const float* __restrict__ W, const float* __restrict__ bias,
    float* __restrict__ C, int M, int N, int K) {
  __shared__ float As[16][17];
  int i0 = blockIdx.x * 16, j0 = blockIdx.y * 64;
  int tx = threadIdx.x & 63, ty = threadIdx.x >> 6;
  int j = j0 + tx;
  float acc[4] = {0.f, 0.f, 0.f, 0.f};
  for (int kk = 0; kk < K; kk += 16) {
    int r = threadIdx.x >> 4, cc = threadIdx.x & 15;
    float av = A[(size_t)(i0 + r) * lda + kk + cc];
    if (avec) av += avec[kk + cc];
    As[r][cc] = av;
    __syncthreads();
#pragma unroll
    for (int kt = 0; kt < 16; ++kt) {
      float w = W[(size_t)(kk + kt) * N + j];
#pragma unroll
      for (int k2 = 0; k2 < 4; ++k2)
        acc[k2] = fmaf(As[ty*4 + k2][kt], w, acc[k2]);
    }
    __syncthreads();
  }
  float bb = bias ? bias[j] : 0.f;
#pragma unroll
  for (int k2 = 0; k2 < 4; ++k2)
    C[(size_t)(i0 + ty*4 + k2) * N + j] = acc[k2] + bb;
}

// ---------------- phase A: high-level sampling chain (one block per batch) ----------------
__global__ __launch_bounds__(256) void k_high(
    const float* __restrict__ cell_ctx, const int* __restrict__ high_mask,
    const float* __restrict__ hv,
    const float* __restrict__ ws_hq0h, const float* __restrict__ ws_g0h,
    const float* __restrict__ ws_Qh, const float* __restrict__ ws_rhigh,
    const float* __restrict__ ws_M1h, const unsigned* __restrict__ ws_hkeys,
    int* __restrict__ ws_hidx, float* __restrict__ ws_hlogp) {
  int b = blockIdx.x, tid = threadIdx.x;
  int lane = tid & 63, w = tid >> 6;
  __shared__ float s[H_], addM[H_], hq0[H_], g0[H_], hvv[H_];
  __shared__ float uarr[NC_];
  __shared__ int prev_s;
  __shared__ unsigned hm_s;
  __shared__ float acc_s;
  hq0[tid] = ws_hq0h[(size_t)b*H_ + tid];
  g0[tid] = ws_g0h[tid];
  hvv[tid] = hv[tid];
  if (tid == 0) {
    unsigned m = 0;
    for (int c = 0; c < NC_; ++c) if (high_mask[b*NC_ + c] > 0) m |= (1u << c);
    hm_s = m; acc_s = 0.f; prev_s = 0;
  }
  __syncthreads();
  for (int t = 0; t < NC_; ++t) {
    {
      float v = hq0[tid];
      if (t == 0) v += g0[tid];
      else        v += addM[tid] + ws_Qh[(size_t)(b*NC_ + prev_s)*H_ + tid];
      s[tid] = v;
    }
    __syncthreads();
    unsigned hm = hm_s;
    for (int q8 = 0; q8 < 8; ++q8) {
      int cidx = w*8 + q8;
      if ((hm >> cidx) & 1u) continue;
      const float* rr = ws_rhigh + (size_t)(b*NC_ + cidx)*H_;
      float a = 0.f;
#pragma unroll
      for (int jj = 0; jj < 4; ++jj) {
        int h = lane + 64*jj;
        a += hvv[h] * ftanh(s[h] + rr[h]);
      }
#pragma unroll
      for (int off = 32; off; off >>= 1) a += __shfl_xor(a, off);
      if (lane == 0) uarr[cidx] = 10.0f * ftanh(a);
    }
    __syncthreads();
    if (w == 0) {
      int cidx = lane;
      bool valid = (cidx < NC_);
      bool masked = valid && ((hm >> cidx) & 1u);
      float logit = valid ? (masked ? -1e9f : uarr[cidx]) : -INFINITY;
      float val = -INFINITY;
      if (valid) {
        float g = gumbel_bits(ws_hkeys[2*t], ws_hkeys[2*t+1],
                              (unsigned)(b*NC_ + cidx));
        val = logit + g;
      }
      float bvv = val; int bi = valid ? cidx : 9999;
#pragma unroll
      for (int off = 32; off; off >>= 1) {
        float ov = __shfl_xor(bvv, off); int oi = __shfl_xor(bi, off);
        if (ov > bvv || (ov == bvv && oi < bi)) { bvv = ov; bi = oi; }
      }
      float m = logit;
#pragma unroll
      for (int off = 32; off; off >>= 1) m = fmaxf(m, __shfl_xor(m, off));
      float ex = (valid && !masked) ? expf(logit - m) : 0.f;
#pragma unroll
      for (int off = 32; off; off >>= 1) ex += __shfl_xor(ex, off);
      float lsel = __shfl(logit, bi);
      float logp = lsel - m - logf(ex);
      if (lane == 0) {
        acc_s += logp;
        ws_hidx[b*NC_ + t] = bi;
        hm_s = hm | (1u << bi);
        prev_s = bi;
      }
    }
    __syncthreads();
    if (t == 0) {
      {
        int idx0 = prev_s;
        const float* crow = cell_ctx + (size_t)(b*NC_ + idx0)*E_;
        float a = 0.f;
        for (int e = 0; e < E_; ++e)
          a = fmaf(crow[e], ws_M1h[(size_t)e*H_ + tid], a);
        addM[tid] = a;
      }
      __syncthreads();
    }
  }
  if (tid == 0) ws_hlogp[b] = acc_s;
}

// ---------------- phase B: low decodes, one block per (b, high-step t) ----------------
#define XR_ROWS 56

__global__ __launch_bounds__(1024) void k_low(
    const float* __restrict__ node_ctx, const float* __restrict__ orig,
    const int* __restrict__ low_mask,
    const float* __restrict__ lWr, const float* __restrict__ lbr,
    const float* __restrict__ lv,
    const float* __restrict__ ws_Al, const float* __restrict__ ws_M1l,
    const float* __restrict__ ws_hq0l, const float* __restrict__ ws_g0l,
    const unsigned* __restrict__ ws_lkeys, const int* __restrict__ ws_hidx,
    float* __restrict__ ws_Q,      // [2048][64][256]
    float* __restrict__ ws_rov,    // [2048][8][256]
    float* __restrict__ ws_llogp, float* __restrict__ ws_lR,
    float* __restrict__ ws_lastn, float* __restrict__ ws_initn) {
  __shared__ __align__(16) float Xr[XR_ROWS * 256];   // 56KB: r rows 0..55
  __shared__ __align__(16) float region_f[1200];      // GEMM stage / step arrays
  int tid = threadIdx.x, lane = tid & 63, w = tid >> 6;
  int bid = blockIdx.x;
  int b = bid >> 5, t = bid & 31;
  int c = ws_hidx[b*NC_ + t];
  const float* ctxg = node_ctx + (size_t)(b*NC_ + c) * NL_ * E_;

  // ---- in-block GEMM: [r | Q] = ctx @ [lWr | Al] (+lbr on r) ----
  {
    float* ctx_s = region_f;           // [64][16]
    float* Wst = Xr;                   // [8][512] staging (aliases Xr, acc in regs)
    int hg = tid & 63, ng = tid >> 6;  // 16 groups x 4 rows
    int jA = hg * 4;
    float accA[4][4], accB[4][4];
    {
      float4 lb4 = *(const float4*)(lbr + jA);
#pragma unroll
      for (int i = 0; i < 4; ++i) {
        accA[i][0] = lb4.x; accA[i][1] = lb4.y; accA[i][2] = lb4.z; accA[i][3] = lb4.w;
        accB[i][0] = 0.f; accB[i][1] = 0.f; accB[i][2] = 0.f; accB[i][3] = 0.f;
      }
    }
    for (int ec = 0; ec < E_; ec += 16) {
      __syncthreads();
      ctx_s[(tid >> 4)*16 + (tid & 15)] = ctxg[(size_t)(tid >> 4)*E_ + ec + (tid & 15)];
      for (int sub = 0; sub < 2; ++sub) {
        __syncthreads();
        {
          int el8 = tid >> 7, jj = (tid & 127) * 4;
          int e = ec + sub*8 + el8;
          const float* src = (jj < 256) ? (lWr + (size_t)e*H_ + jj)
                                        : (ws_Al + (size_t)e*H_ + (jj - 256));
          *(float4*)&Wst[el8*512 + jj] = *(const float4*)src;
        }
        __syncthreads();
#pragma unroll
        for (int half = 0; half < 2; ++half) {
          float crr[4][4];
#pragma unroll
          for (int i = 0; i < 4; ++i) {
            float4 c4 = *(const float4*)&ctx_s[(ng*4 + i)*16 + sub*8 + half*4];
            crr[i][0] = c4.x; crr[i][1] = c4.y; crr[i][2] = c4.z; crr[i][3] = c4.w;
          }
#pragma unroll
          for (int el = 0; el < 4; ++el) {
            int er = half*4 + el;
            float4 wA = *(const float4*)&Wst[er*512 + jA];
            float4 wB = *(const float4*)&Wst[er*512 + 256 + jA];
#pragma unroll
            for (int i = 0; i < 4; ++i) {
              float ce = crr[i][el];
              accA[i][0] = fmaf(ce, wA.x, accA[i][0]);
              accA[i][1] = fmaf(ce, wA.y, accA[i][1]);
              accA[i][2] = fmaf(ce, wA.z, accA[i][2]);
              accA[i][3] = fmaf(ce, wA.w, accA[i][3]);
              accB[i][0] = fmaf(ce, wB.x, accB[i][0]);
              accB[i][1] = fmaf(ce, wB.y, accB[i][1]);
              accB[i][2] = fmaf(ce, wB.z, accB[i][2]);
              accB[i][3] = fmaf(ce, wB.w, accB[i][3]);
            }
          }
        }
      }
    }
    __syncthreads();
#pragma unroll
    for (int i = 0; i < 4; ++i) {
      int n = ng*4 + i;
      float4 vA = make_float4(accA[i][0], accA[i][1], accA[i][2], accA[i][3]);
      float4 vB = make_float4(accB[i][0], accB[i][1], accB[i][2], accB[i][3]);
      if (n < XR_ROWS) *(float4*)&Xr[n*256 + jA] = vA;
      else *(float4*)(ws_rov + ((size_t)bid*8 + (n - XR_ROWS))*256 + jA) = vA;
      *(float4*)(ws_Q + ((size_t)bid*64 + n)*256 + jA) = vB;
    }
  }
  __syncthreads();

  // ---- step arrays (alias GEMM stage region) ----
  float* sbase  = region_f;                 // 256
  float* svec   = region_f + 256;           // 256
  float* lvv    = region_f + 512;           // 256
  float* coords = region_f + 768;           // 128
  float* uarr   = region_f + 896;           // 64
  unsigned* skeys = (unsigned*)(region_f + 960);  // 128
  int* maskf    = (int*)(region_f + 1088);  // 64
  int* scal     = (int*)(region_f + 1152);  // [0]=prev [1]=cur
  float* facc   = region_f + 1156;          // [0]=llogp [1]=lR

  if (tid < 256) lvv[tid] = lv[tid];
  if (tid >= 256 && tid < 384) coords[tid - 256] = orig[(size_t)(b*NC_ + c)*NL_*2 + (tid - 256)];
  if (tid >= 384 && tid < 448) maskf[tid - 384] = low_mask[(size_t)(b*NC_ + c)*NL_ + (tid - 384)];
  if (tid >= 448 && tid < 512) {
    int j = tid - 448;
    unsigned a, bb;
    tf2x32(ws_lkeys[2*t], ws_lkeys[2*t+1], 0u, (unsigned)j, a, bb);  // split(lkeys[t],64)[j]
    skeys[2*j] = a; skeys[2*j+1] = bb;
  }
  if (tid == 0) { scal[0] = 0; scal[1] = 0; facc[0] = 0.f; facc[1] = 0.f; }
  __syncthreads();

  const float* hq0row = ws_hq0l + (size_t)(b*NC_ + c)*H_;

  for (int s = 0; s < NL_; ++s) {
    if (tid < 256) {
      float v;
      if (s == 0) v = hq0row[tid] + ws_g0l[tid];
      else        v = sbase[tid] + ws_Q[((size_t)bid*64 + scal[0])*256 + tid];
      svec[tid] = v;
    }
    __syncthreads();
#pragma unroll
    for (int k = 0; k < 4; ++k) {
      int n = w*4 + k;
      if (maskf[n]) continue;
      const float* rrow = (n < XR_ROWS) ? &Xr[n*256]
                                        : (ws_rov + ((size_t)bid*8 + (n - XR_ROWS))*256);
      float a = 0.f;
#pragma unroll
      for (int jj = 0; jj < 4; ++jj) {
        int h = lane + 64*jj;
        a += lvv[h] * ftanh(svec[h] + rrow[h]);
      }
#pragma unroll
      for (int off = 32; off; off >>= 1) a += __shfl_xor(a, off);
      if (lane == 0) uarr[n] = 10.0f * ftanh(a);
    }
    __syncthreads();
    if (w == 0) {
      int n = lane;
      bool masked = (maskf[n] != 0);
      float logit = masked ? -1e9f : uarr[n];
      float g = gumbel_bits(skeys[2*s], skeys[2*s+1], (unsigned)(b*NL_ + n));
      float val = logit + g;
      float bvv = val; int bi = n;
#pragma unroll
      for (int off = 32; off; off >>= 1) {
        float ov = __shfl_xor(bvv, off); int oi = __shfl_xor(bi, off);
        if (ov > bvv || (ov == bvv && oi < bi)) { bvv = ov; bi = oi; }
      }
      float m = logit;
#pragma unroll
      for (int off = 32; off; off >>= 1) m = fmaxf(m, __shfl_xor(m, off));
      float ex = masked ? 0.f : expf(logit - m);
#pragma unroll
      for (int off = 32; off; off >>= 1) ex += __shfl_xor(ex, off);
      float lsel = __shfl(logit, bi);
      float logp = lsel - m - logf(ex);
      if (lane == 0) {
        facc[0] += logp;
        int cur = scal[1];
        float dx = coords[2*bi] - coords[2*cur];
        float dy = coords[2*bi+1] - coords[2*cur+1];
        facc[1] += sqrtf(dx*dx + dy*dy + 1e-12f);
        scal[1] = bi; scal[0] = bi; maskf[bi] = 1;
      }
    }
    __syncthreads();
    if (s == 0) {
      if (tid < 256) {
        int idx0 = scal[0];
        const float* crow = ctxg + (size_t)idx0 * E_;
        float a = hq0row[tid];
        for (int e = 0; e < E_; ++e)
          a = fmaf(crow[e], ws_M1l[(size_t)e*H_ + tid], a);
        sbase[tid] = a;
      }
      __syncthreads();
    }
  }
  if (tid == 0) {
    int o = b*NC_ + t;
    ws_llogp[o] = facc[0];
    ws_lR[o] = facc[1];
    int last = scal[1];
    ws_lastn[2*o] = coords[2*last]; ws_lastn[2*o+1] = coords[2*last+1];
    ws_initn[2*o] = coords[0];      ws_initn[2*o+1] = coords[1];
  }
}

// ---------------- phase C: stitch ----------------
__global__ __launch_bounds__(64) void k_stitch(
    const float* __restrict__ ws_hlogp, const float* __restrict__ ws_llogp,
    const float* __restrict__ ws_lR, const float* __restrict__ ws_lastn,
    const float* __restrict__ ws_initn, float* __restrict__ out) {
  int b = threadIdx.x;
  if (b >= B_) return;
  float lp = ws_hlogp[b], rw = 0.f, lx = 0.f, ly = 0.f;
  for (int t = 0; t < NC_; ++t) {
    int o = b*NC_ + t;
    lp += ws_llogp[o];
    float dx = ws_initn[2*o] - lx, dy = ws_initn[2*o+1] - ly;
    rw += ws_lR[o] + sqrtf(dx*dx + dy*dy + 1e-12f);
    lx = ws_lastn[2*o]; ly = ws_lastn[2*o+1];
  }
  out[b] = lp;
  out[B_ + b] = rw;
}

// ---------------- host launcher ----------------
extern "C" void kernel_launch(void* const* d_in, const int* in_sizes, int n_in,
                              void* d_out, int out_size, void* d_ws, size_t ws_size,
                              hipStream_t stream) {
  const float* node_ctx  = (const float*)d_in[0];
  const float* cell_ctx  = (const float*)d_in[1];
  const float* orig      = (const float*)d_in[2];
  const int*   high_mask = (const int*)d_in[3];
  const int*   low_mask  = (const int*)d_in[4];
  const float* init_w    = (const float*)d_in[5];
  const float* Wc        = (const float*)d_in[6];
  const float* bc        = (const float*)d_in[7];
  const float* Wv        = (const float*)d_in[8];
  const float* bv        = (const float*)d_in[9];
  const float* hWq       = (const float*)d_in[10];
  const float* hbq       = (const float*)d_in[11];
  const float* hWr       = (const float*)d_in[12];
  const float* hbr       = (const float*)d_in[13];
  const float* hv        = (const float*)d_in[14];
  const float* low_init_w= (const float*)d_in[15];
  const float* lWc       = (const float*)d_in[16];
  const float* lbc       = (const float*)d_in[17];
  const float* lWv       = (const float*)d_in[18];
  const float* lbv       = (const float*)d_in[19];
  const float* lWq       = (const float*)d_in[20];
  const float* lbq       = (const float*)d_in[21];
  const float* lWr       = (const float*)d_in[22];
  const float* lbr       = (const float*)d_in[23];
  const float* lv        = (const float*)d_in[24];
  float* out = (float*)d_out;

  char* ws = (char*)d_ws;
  size_t off = 0;
  auto alloc = [&](size_t bytes) -> void* {
    void* p = ws + off;
    off += (bytes + 255) & ~(size_t)255;
    return p;
  };
  unsigned* w_hkeys = (unsigned*)alloc(32*2*4);
  unsigned* w_lkeys = (unsigned*)alloc(32*2*4);
  int*   w_hidx  = (int*)alloc(2048*4);
  float* w_hlogp = (float*)alloc(64*4);
  float* w_llogp = (float*)alloc(2048*4);
  float* w_lR    = (float*)alloc(2048*4);
  float* w_lastn = (float*)alloc(2048*2*4);
  float* w_initn = (float*)alloc(2048*2*4);
  float* w_g0h   = (float*)alloc(256*4);
  float* w_g0l   = (float*)alloc(256*4);
  float* w_M1h   = (float*)alloc((size_t)65536*4);
  float* w_Ah    = (float*)alloc((size_t)65536*4);
  float* w_M1l   = (float*)alloc((size_t)65536*4);
  float* w_Al    = (float*)alloc((size_t)65536*4);
  float* w_mcc   = (float*)alloc((size_t)64*256*4);
  float* w_mnc   = (float*)alloc((size_t)2048*256*4);
  float* w_hbh   = (float*)alloc((size_t)64*256*4);
  float* w_hq0h  = (float*)alloc((size_t)64*256*4);
  float* w_rhigh = (float*)alloc((size_t)2048*256*4);
  float* w_Qh    = (float*)alloc((size_t)2048*256*4);
  float* w_hbl   = (float*)alloc((size_t)2048*256*4);
  float* w_hq0l  = (float*)alloc((size_t)2048*256*4);
  float* w_Q     = (float*)alloc((size_t)2048*64*256*4);   // 134 MB
  float* w_rov   = (float*)alloc((size_t)2048*8*256*4);    // 16.8 MB
  (void)ws_size; (void)in_sizes; (void)n_in; (void)out_size;

  k0_kernel<<<1, 256, 0, stream>>>(init_w, Wv, hWq, low_init_w, lWv, lWq,
                                   w_hkeys, w_lkeys, w_g0h, w_g0l);
  k_mean<<<2048, 256, 0, stream>>>(node_ctx, w_mnc, 64);
  k_mean<<<64, 256, 0, stream>>>(cell_ctx, w_mcc, 32);

  dim3 g256(16, 4), g2048(128, 4), g64(4, 4);
  // M1h = Wv1@hWq ; Ah = Wv2@hWq ; M1l = lWv1@lWq ; Al = lWv2@lWq
  k_gemm<<<g256, 256, 0, stream>>>(Wv,            256, nullptr, hWq, nullptr, w_M1h, 256, 256, 256);
  k_gemm<<<g256, 256, 0, stream>>>(Wv + 65536,    256, nullptr, hWq, nullptr, w_Ah,  256, 256, 256);
  k_gemm<<<g256, 256, 0, stream>>>(lWv,           256, nullptr, lWq, nullptr, w_M1l, 256, 256, 256);
  k_gemm<<<g256, 256, 0, stream>>>(lWv + 65536,   256, nullptr, lWq, nullptr, w_Al,  256, 256, 256);
  // r_high = cc@hWr + hbr ; Qh_all = cc@Ah
  k_gemm<<<g2048, 256, 0, stream>>>(cell_ctx, 256, nullptr, hWr, hbr, w_rhigh, 2048, 256, 256);
  k_gemm<<<g2048, 256, 0, stream>>>(cell_ctx, 256, nullptr, w_Ah, nullptr, w_Qh, 2048, 256, 256);
  // h_bar
  k_gemm<<<g64,   256, 0, stream>>>(w_mcc, 256, nullptr, Wc,  bc,  w_hbh, 64,   256, 256);
  k_gemm<<<g2048, 256, 0, stream>>>(w_mnc, 256, nullptr, lWc, lbc, w_hbl, 2048, 256, 256);
  // hq0 = (h_bar + bv)@Wq + bq
  k_gemm<<<g64,   256, 0, stream>>>(w_hbh, 256, bv,  hWq, hbq, w_hq0h, 64,   256, 256);
  k_gemm<<<g2048, 256, 0, stream>>>(w_hbl, 256, lbv, lWq, lbq, w_hq0l, 2048, 256, 256);

  k_high<<<64, 256, 0, stream>>>(cell_ctx, high_mask, hv, w_hq0h, w_g0h, w_Qh,
                                 w_rhigh, w_M1h, w_hkeys, w_hidx, w_hlogp);
  k_low<<<2048, 1024, 0, stream>>>(node_ctx, orig, low_mask, lWr, lbr, lv,
                                   w_Al, w_M1l, w_hq0l, w_g0l, w_lkeys, w_hidx,
                                   w_Q, w_rov, w_llogp, w_lR, w_lastn, w_initn);
  k_stitch<<<1, 64, 0, stream>>>(w_hlogp, w_llogp, w_lR, w_lastn, w_initn, out);
}

// Round 2
// 2411.554 us; speedup vs baseline: 1.3593x; 1.3593x over previous
//
#include <hip/hip_runtime.h>
#include <cstdint>
#include <cstddef>

#define B_  64
#define NC_ 32
#define NL_ 64
#define E_  256
#define H_  256

// ---------------- Threefry-2x32, 20 rounds (JAX-compatible) ----------------
__device__ __forceinline__ void tf2x32(unsigned k0, unsigned k1,
                                       unsigned c0, unsigned c1,
                                       unsigned &o0, unsigned &o1) {
  unsigned ks2 = k0 ^ k1 ^ 0x1BD11BDAu;
  unsigned x0 = c0 + k0, x1 = c1 + k1;
#define TFR(r) { x0 += x1; x1 = (x1 << r) | (x1 >> (32 - r)); x1 ^= x0; }
  TFR(13) TFR(15) TFR(26) TFR(6)   x0 += k1;  x1 += ks2 + 1u;
  TFR(17) TFR(29) TFR(16) TFR(24)  x0 += ks2; x1 += k0 + 2u;
  TFR(13) TFR(15) TFR(26) TFR(6)   x0 += k0;  x1 += k1 + 3u;
  TFR(17) TFR(29) TFR(16) TFR(24)  x0 += k1;  x1 += ks2 + 4u;
  TFR(13) TFR(15) TFR(26) TFR(6)   x0 += ks2; x1 += k0 + 5u;
#undef TFR
  o0 = x0; o1 = x1;
}

__device__ __forceinline__ float gumbel_bits(unsigned k0, unsigned k1, unsigned flat) {
  unsigned a, b;
  tf2x32(k0, k1, 0u, flat, a, b);
  unsigned bits = a ^ b;
  float f = __uint_as_float(0x3F800000u | (bits >> 9)) - 1.0f;
  f = fmaxf(f, 1.17549435e-38f);
  return -logf(-logf(f));
}

__device__ __forceinline__ float ftanh(float x) {
  return 1.0f - 2.0f / (__expf(2.0f * x) + 1.0f);
}

// ---------------- K0: keys + init vectors ----------------
__global__ __launch_bounds__(256) void k0_kernel(
    const float* __restrict__ init_w, const float* __restrict__ Wv,
    const float* __restrict__ hWq,
    const float* __restrict__ low_init_w, const float* __restrict__ lWv,
    const float* __restrict__ lWq,
    unsigned* __restrict__ hkeys, unsigned* __restrict__ lkeys,
    float* __restrict__ g0h, float* __restrict__ g0l) {
  int tid = threadIdx.x;
  __shared__ float s_iwv[E_], s_liwv[E_];
  if (tid < 32) {
    unsigned a, b;
    tf2x32(0u, 42u, 0u, (unsigned)tid, a, b);
    hkeys[2*tid] = a; hkeys[2*tid+1] = b;
    tf2x32(0u, 7u, 0u, (unsigned)tid, a, b);
    lkeys[2*tid] = a; lkeys[2*tid+1] = b;
  }
  {
    float a = 0.f, a2 = 0.f;
    for (int k = 0; k < 2*E_; ++k) {
      a  = fmaf(init_w[k],     Wv[(size_t)k*E_ + tid], a);
      a2 = fmaf(low_init_w[k], lWv[(size_t)k*E_ + tid], a2);
    }
    s_iwv[tid] = a; s_liwv[tid] = a2;
  }
  __syncthreads();
  {
    float a = 0.f, a2 = 0.f;
    for (int e = 0; e < E_; ++e) {
      a  = fmaf(s_iwv[e],  hWq[(size_t)e*H_ + tid], a);
      a2 = fmaf(s_liwv[e], lWq[(size_t)e*H_ + tid], a2);
    }
    g0h[tid] = a; g0l[tid] = a2;
  }
}

// ---------------- means over middle dim ----------------
__global__ __launch_bounds__(256) void k_mean(const float* __restrict__ in,
                                              float* __restrict__ out, int G) {
  int row = blockIdx.x, h = threadIdx.x;
  const float* p = in + (size_t)row * G * E_ + h;
  float a = 0.f;
  for (int g = 0; g < G; ++g) a += p[(size_t)g * E_];
  out[(size_t)row * E_ + h] = a * (1.0f / G);
}

// ---------------- generic small GEMM: C = (A .+ avec) @ W + bias ----------------
__global__ __launch_bounds__(256) void k_gemm(
    const float* __restrict__ A, int lda, const float* __restrict__ avec,
    const float* __restrict__ W, const float* __restrict__ bias,
    float* __restrict__ C, int M, int N, int K) {
  __shared__ float As[16][17];
  int i0 = blockIdx.x * 16, j0 = blockIdx.y * 64;
  int tx = threadIdx.x & 63, ty = threadIdx.x >> 6;
  int j = j0 + tx;
  float acc[4] = {0.f, 0.f, 0.f, 0.f};
  for (int kk = 0; kk < K; kk += 16) {
    int r = threadIdx.x >> 4, cc = threadIdx.x & 15;
    float av = A[(size_t)(i0 + r) * lda + kk + cc];
    if (avec) av += avec[kk + cc];
    As[r][cc] = av;
    __syncthreads();
#pragma unroll
    for (int kt = 0; kt < 16; ++kt) {
      float w = W[(size_t)(kk + kt) * N + j];
#pragma unroll
      for (int k2 = 0; k2 < 4; ++k2)
        acc[k2] = fmaf(As[ty*4 + k2][kt], w, acc[k2]);
    }
    __syncthreads();
  }
  float bb = bias ? bias[j] : 0.f;
#pragma unroll
  for (int k2 = 0; k2 < 4; ++k2)
    C[(size_t)(i0 + ty*4 + k2) * N + j] = acc[k2] + bb;
}

// ---------------- big GEMM: [R|Q] = node_ctx(131072x256) @ [lWr | Al](256x512) ----------------
// Tile 128x128, KB=16, 256 threads, 8x8 micro-tile per thread.
__global__ __launch_bounds__(256, 2) void k_bgemm(
    const float* __restrict__ A, const float* __restrict__ Wr,
    const float* __restrict__ Alm, const float* __restrict__ lbr,
    float* __restrict__ Rout, float* __restrict__ Qout) {
  __shared__ float As[16][132];   // transposed A tile: As[k][m]
  __shared__ float Ws[16][132];   // W tile: Ws[k][c]
  int bx = blockIdx.x, by = blockIdx.y;
  const float* Wbase = (by < 2) ? Wr : Alm;
  float* Cbase = (by < 2) ? Rout : Qout;
  int jb = (by & 1) * 128;
  bool doBias = (by < 2);
  int m0 = bx * 128;
  int tid = threadIdx.x;
  int tx = tid & 15, ty = tid >> 4;   // c0 = tx*8, r0 = ty*8
  float acc[8][8];
#pragma unroll
  for (int i = 0; i < 8; ++i)
#pragma unroll
    for (int j = 0; j < 8; ++j) acc[i][j] = 0.f;

  for (int kc = 0; kc < 256; kc += 16) {
    {
      int kq = (tid & 3) * 4;
#pragma unroll
      for (int p = 0; p < 2; ++p) {
        int m = (tid >> 2) + p * 64;
        float4 a4 = *(const float4*)&A[(size_t)(m0 + m) * 256 + kc + kq];
        As[kq + 0][m] = a4.x; As[kq + 1][m] = a4.y;
        As[kq + 2][m] = a4.z; As[kq + 3][m] = a4.w;
      }
      int k = tid >> 4;
      int c4 = (tid & 15) * 8;
      float4 w0 = *(const float4*)&Wbase[(size_t)(kc + k) * 256 + jb + c4];
      float4 w1 = *(const float4*)&Wbase[(size_t)(kc + k) * 256 + jb + c4 + 4];
      *(float4*)&Ws[k][c4] = w0;
      *(float4*)&Ws[k][c4 + 4] = w1;
    }
    __syncthreads();
#pragma unroll
    for (int k = 0; k < 16; ++k) {
      float4 a0 = *(float4*)&As[k][ty * 8];
      float4 a1 = *(float4*)&As[k][ty * 8 + 4];
      float4 w0 = *(float4*)&Ws[k][tx * 8];
      float4 w1 = *(float4*)&Ws[k][tx * 8 + 4];
      float av[8] = {a0.x, a0.y, a0.z, a0.w, a1.x, a1.y, a1.z, a1.w};
      float wv[8] = {w0.x, w0.y, w0.z, w0.w, w1.x, w1.y, w1.z, w1.w};
#pragma unroll
      for (int i = 0; i < 8; ++i)
#pragma unroll
        for (int j = 0; j < 8; ++j)
          acc[i][j] = fmaf(av[i], wv[j], acc[i][j]);
    }
    __syncthreads();
  }
  float bias[8];
#pragma unroll
  for (int j = 0; j < 8; ++j)
    bias[j] = doBias ? lbr[jb + tx * 8 + j] : 0.f;
#pragma unroll
  for (int i = 0; i < 8; ++i) {
    float4 o0 = make_float4(acc[i][0] + bias[0], acc[i][1] + bias[1],
                            acc[i][2] + bias[2], acc[i][3] + bias[3]);
    float4 o1 = make_float4(acc[i][4] + bias[4], acc[i][5] + bias[5],
                            acc[i][6] + bias[6], acc[i][7] + bias[7]);
    size_t base = (size_t)(m0 + ty * 8 + i) * 256 + jb + tx * 8;
    *(float4*)&Cbase[base] = o0;
    *(float4*)&Cbase[base + 4] = o1;
  }
}

// ---------------- phase A: high-level sampling chain ----------------
__global__ __launch_bounds__(256) void k_high(
    const float* __restrict__ cell_ctx, const int* __restrict__ high_mask,
    const float* __restrict__ hv,
    const float* __restrict__ ws_hq0h, const float* __restrict__ ws_g0h,
    const float* __restrict__ ws_Qh, const float* __restrict__ ws_rhigh,
    const float* __restrict__ ws_M1h, const unsigned* __restrict__ ws_hkeys,
    int* __restrict__ ws_hidx, float* __restrict__ ws_hlogp) {
  int b = blockIdx.x, tid = threadIdx.x;
  int lane = tid & 63, w = tid >> 6;
  __shared__ float s[H_], addM[H_], hq0[H_], g0[H_], hvv[H_];
  __shared__ float uarr[NC_];
  __shared__ int prev_s;
  __shared__ unsigned hm_s;
  __shared__ float acc_s;
  hq0[tid] = ws_hq0h[(size_t)b*H_ + tid];
  g0[tid] = ws_g0h[tid];
  hvv[tid] = hv[tid];
  if (tid == 0) {
    unsigned m = 0;
    for (int c = 0; c < NC_; ++c) if (high_mask[b*NC_ + c] > 0) m |= (1u << c);
    hm_s = m; acc_s = 0.f; prev_s = 0;
  }
  __syncthreads();
  for (int t = 0; t < NC_; ++t) {
    {
      float v = hq0[tid];
      if (t == 0) v += g0[tid];
      else        v += addM[tid] + ws_Qh[(size_t)(b*NC_ + prev_s)*H_ + tid];
      s[tid] = v;
    }
    __syncthreads();
    unsigned hm = hm_s;
    for (int q8 = 0; q8 < 8; ++q8) {
      int cidx = w*8 + q8;
      if ((hm >> cidx) & 1u) continue;
      const float* rr = ws_rhigh + (size_t)(b*NC_ + cidx)*H_;
      float a = 0.f;
#pragma unroll
      for (int jj = 0; jj < 4; ++jj) {
        int h = lane + 64*jj;
        a += hvv[h] * ftanh(s[h] + rr[h]);
      }
#pragma unroll
      for (int off = 32; off; off >>= 1) a += __shfl_xor(a, off);
      if (lane == 0) uarr[cidx] = 10.0f * ftanh(a);
    }
    __syncthreads();
    if (w == 0) {
      int cidx = lane;
      bool valid = (cidx < NC_);
      bool masked = valid && ((hm >> cidx) & 1u);
      float logit = valid ? (masked ? -1e9f : uarr[cidx]) : -INFINITY;
      float val = -INFINITY;
      if (valid) {
        float g = gumbel_bits(ws_hkeys[2*t], ws_hkeys[2*t+1],
                              (unsigned)(b*NC_ + cidx));
        val = logit + g;
      }
      float bvv = val; int bi = valid ? cidx : 9999;
#pragma unroll
      for (int off = 32; off; off >>= 1) {
        float ov = __shfl_xor(bvv, off); int oi = __shfl_xor(bi, off);
        if (ov > bvv || (ov == bvv && oi < bi)) { bvv = ov; bi = oi; }
      }
      float m = logit;
#pragma unroll
      for (int off = 32; off; off >>= 1) m = fmaxf(m, __shfl_xor(m, off));
      float ex = (valid && !masked) ? expf(logit - m) : 0.f;
#pragma unroll
      for (int off = 32; off; off >>= 1) ex += __shfl_xor(ex, off);
      float lsel = __shfl(logit, bi);
      float logp = lsel - m - logf(ex);
      if (lane == 0) {
        acc_s += logp;
        ws_hidx[b*NC_ + t] = bi;
        hm_s = hm | (1u << bi);
        prev_s = bi;
      }
    }
    __syncthreads();
    if (t == 0) {
      {
        int idx0 = prev_s;
        const float* crow = cell_ctx + (size_t)(b*NC_ + idx0)*E_;
        float a = 0.f;
        for (int e = 0; e < E_; ++e)
          a = fmaf(crow[e], ws_M1h[(size_t)e*H_ + tid], a);
        addM[tid] = a;
      }
      __syncthreads();
    }
  }
  if (tid == 0) ws_hlogp[b] = acc_s;
}

// ---------------- phase B2: low step loop, 256 threads, r in registers ----------------
__global__ __launch_bounds__(256, 4) void k_lowstep(
    const float* __restrict__ node_ctx, const float* __restrict__ orig,
    const int* __restrict__ low_mask, const float* __restrict__ lv,
    const float* __restrict__ ws_R, const float* __restrict__ ws_Qm,
    const float* __restrict__ ws_M1l, const float* __restrict__ ws_hq0l,
    const float* __restrict__ ws_g0l, const unsigned* __restrict__ ws_lkeys,
    const int* __restrict__ ws_hidx,
    float* __restrict__ ws_llogp, float* __restrict__ ws_lR,
    float* __restrict__ ws_lastn, float* __restrict__ ws_initn) {
  __shared__ float svec[256], sbase[256], qrow[256];
  __shared__ float coords[128], uarr[64];
  __shared__ unsigned skeys[128];
  __shared__ unsigned long long smask;
  __shared__ int scal[2];          // [0]=prev [1]=cur
  __shared__ float facc[2];        // [0]=llogp [1]=lR
  int tid = threadIdx.x, lane = tid & 63, w = tid >> 6;
  int bid = blockIdx.x, b = bid >> 5, t = bid & 31;
  int c = ws_hidx[b*NC_ + t];
  int cell = b*NC_ + c;
  const float* ctxg = node_ctx + (size_t)cell * NL_ * E_;

  // r rows -> registers: wave w owns rows w*16 .. w*16+15, lane covers h=lane+64j
  float rr[16][4];
  {
    const float* Rb = ws_R + (size_t)cell * NL_ * E_;
#pragma unroll
    for (int i = 0; i < 16; ++i) {
      int n = w*16 + i;
#pragma unroll
      for (int j = 0; j < 4; ++j)
        rr[i][j] = Rb[(size_t)n*E_ + lane + 64*j];
    }
  }
  float lvreg[4];
#pragma unroll
  for (int j = 0; j < 4; ++j) lvreg[j] = lv[lane + 64*j];

  if (tid < 128) coords[tid] = orig[(size_t)cell*NL_*2 + tid];
  if (tid >= 128 && tid < 192) {
    int j = tid - 128;
    unsigned a, bb;
    tf2x32(ws_lkeys[2*t], ws_lkeys[2*t+1], 0u, (unsigned)j, a, bb);
    skeys[2*j] = a; skeys[2*j+1] = bb;
  }
  if (tid == 0) {
    unsigned long long m = 0;
    for (int n = 0; n < NL_; ++n)
      if (low_mask[(size_t)cell*NL_ + n] > 0) m |= (1ull << n);
    smask = m; scal[0] = 0; scal[1] = 0; facc[0] = 0.f; facc[1] = 0.f;
  }
  const float* hq0row = ws_hq0l + (size_t)cell * H_;
  __syncthreads();

  for (int s = 0; s < NL_; ++s) {
    if (s == 0) svec[tid] = hq0row[tid] + ws_g0l[tid];
    else        svec[tid] = sbase[tid] + qrow[tid];
    __syncthreads();
    unsigned long long mask = smask;
    float sv[4];
#pragma unroll
    for (int j = 0; j < 4; ++j) sv[j] = svec[lane + 64*j];
#pragma unroll
    for (int i = 0; i < 16; ++i) {
      int n = w*16 + i;
      if ((mask >> n) & 1ull) continue;
      float a = 0.f;
#pragma unroll
      for (int j = 0; j < 4; ++j)
        a = fmaf(lvreg[j], ftanh(sv[j] + rr[i][j]), a);
#pragma unroll
      for (int off = 32; off; off >>= 1) a += __shfl_xor(a, off);
      if (lane == 0) uarr[n] = 10.0f * ftanh(a);
    }
    __syncthreads();
    if (w == 0) {
      int n = lane;
      bool masked = (mask >> n) & 1ull;
      float logit = masked ? -1e9f : uarr[n];
      float g = gumbel_bits(skeys[2*s], skeys[2*s+1], (unsigned)(b*NL_ + n));
      float val = logit + g;
      float bvv = val; int bi = n;
#pragma unroll
      for (int off = 32; off; off >>= 1) {
        float ov = __shfl_xor(bvv, off); int oi = __shfl_xor(bi, off);
        if (ov > bvv || (ov == bvv && oi < bi)) { bvv = ov; bi = oi; }
      }
      // prefetch Q[bi] while softmax tail computes
      float4 q4 = *(const float4*)(ws_Qm + ((size_t)cell*NL_ + bi)*E_ + 4*lane);
      float m = logit;
#pragma unroll
      for (int off = 32; off; off >>= 1) m = fmaxf(m, __shfl_xor(m, off));
      float ex = masked ? 0.f : expf(logit - m);
#pragma unroll
      for (int off = 32; off; off >>= 1) ex += __shfl_xor(ex, off);
      float lsel = __shfl(logit, bi);
      float logp = lsel - m - logf(ex);
      if (lane == 0) {
        facc[0] += logp;
        int cur = scal[1];
        float dx = coords[2*bi] - coords[2*cur];
        float dy = coords[2*bi+1] - coords[2*cur+1];
        facc[1] += sqrtf(dx*dx + dy*dy + 1e-12f);
        scal[1] = bi; scal[0] = bi;
        smask = mask | (1ull << bi);
      }
      *(float4*)&qrow[4*lane] = q4;
    }
    __syncthreads();
    if (s == 0) {
      // sbase[tid] = hq0 + ctx[idx0] @ M1l  (own-write/own-read; no barrier needed)
      int idx0 = scal[0];
      const float* crow = ctxg + (size_t)idx0 * E_;
      float a = hq0row[tid];
      for (int e = 0; e < E_; ++e)
        a = fmaf(crow[e], ws_M1l[(size_t)e*H_ + tid], a);
      sbase[tid] = a;
    }
  }
  if (tid == 0) {
    int o = b*NC_ + t;
    ws_llogp[o] = facc[0];
    ws_lR[o] = facc[1];
    int last = scal[1];
    ws_lastn[2*o] = coords[2*last]; ws_lastn[2*o+1] = coords[2*last+1];
    ws_initn[2*o] = coords[0];      ws_initn[2*o+1] = coords[1];
  }
}

// ---------------- phase C: stitch ----------------
__global__ __launch_bounds__(64) void k_stitch(
    const float* __restrict__ ws_hlogp, const float* __restrict__ ws_llogp,
    const float* __restrict__ ws_lR, const float* __restrict__ ws_lastn,
    const float* __restrict__ ws_initn, float* __restrict__ out) {
  int b = threadIdx.x;
  if (b >= B_) return;
  float lp = ws_hlogp[b], rw = 0.f, lx = 0.f, ly = 0.f;
  for (int t = 0; t < NC_; ++t) {
    int o = b*NC_ + t;
    lp += ws_llogp[o];
    float dx = ws_initn[2*o] - lx, dy = ws_initn[2*o+1] - ly;
    rw += ws_lR[o] + sqrtf(dx*dx + dy*dy + 1e-12f);
    lx = ws_lastn[2*o]; ly = ws_lastn[2*o+1];
  }
  out[b] = lp;
  out[B_ + b] = rw;
}

// ---------------- host launcher ----------------
extern "C" void kernel_launch(void* const* d_in, const int* in_sizes, int n_in,
                              void* d_out, int out_size, void* d_ws, size_t ws_size,
                              hipStream_t stream) {
  const float* node_ctx  = (const float*)d_in[0];
  const float* cell_ctx  = (const float*)d_in[1];
  const float* orig      = (const float*)d_in[2];
  const int*   high_mask = (const int*)d_in[3];
  const int*   low_mask  = (const int*)d_in[4];
  const float* init_w    = (const float*)d_in[5];
  const float* Wc        = (const float*)d_in[6];
  const float* bc        = (const float*)d_in[7];
  const float* Wv        = (const float*)d_in[8];
  const float* bv        = (const float*)d_in[9];
  const float* hWq       = (const float*)d_in[10];
  const float* hbq       = (const float*)d_in[11];
  const float* hWr       = (const float*)d_in[12];
  const float* hbr       = (const float*)d_in[13];
  const float* hv        = (const float*)d_in[14];
  const float* low_init_w= (const float*)d_in[15];
  const float* lWc       = (const float*)d_in[16];
  const float* lbc       = (const float*)d_in[17];
  const float* lWv       = (const float*)d_in[18];
  const float* lbv       = (const float*)d_in[19];
  const float* lWq       = (const float*)d_in[20];
  const float* lbq       = (const float*)d_in[21];
  const float* lWr       = (const float*)d_in[22];
  const float* lbr       = (const float*)d_in[23];
  const float* lv        = (const float*)d_in[24];
  float* out = (float*)d_out;

  char* ws = (char*)d_ws;
  size_t off = 0;
  auto alloc = [&](size_t bytes) -> void* {
    void* p = ws + off;
    off += (bytes + 255) & ~(size_t)255;
    return p;
  };
  unsigned* w_hkeys = (unsigned*)alloc(32*2*4);
  unsigned* w_lkeys = (unsigned*)alloc(32*2*4);
  int*   w_hidx  = (int*)alloc(2048*4);
  float* w_hlogp = (float*)alloc(64*4);
  float* w_llogp = (float*)alloc(2048*4);
  float* w_lR    = (float*)alloc(2048*4);
  float* w_lastn = (float*)alloc(2048*2*4);
  float* w_initn = (float*)alloc(2048*2*4);
  float* w_g0h   = (float*)alloc(256*4);
  float* w_g0l   = (float*)alloc(256*4);
  float* w_M1h   = (float*)alloc((size_t)65536*4);
  float* w_Ah    = (float*)alloc((size_t)65536*4);
  float* w_M1l   = (float*)alloc((size_t)65536*4);
  float* w_Al    = (float*)alloc((size_t)65536*4);
  float* w_mcc   = (float*)alloc((size_t)64*256*4);
  float* w_mnc   = (float*)alloc((size_t)2048*256*4);
  float* w_hbh   = (float*)alloc((size_t)64*256*4);
  float* w_hq0h  = (float*)alloc((size_t)64*256*4);
  float* w_rhigh = (float*)alloc((size_t)2048*256*4);
  float* w_Qh    = (float*)alloc((size_t)2048*256*4);
  float* w_hbl   = (float*)alloc((size_t)2048*256*4);
  float* w_hq0l  = (float*)alloc((size_t)2048*256*4);
  float* w_R     = (float*)alloc((size_t)2048*64*256*4);   // 134 MB
  float* w_Qm    = (float*)alloc((size_t)2048*64*256*4);   // 134 MB
  (void)ws_size; (void)in_sizes; (void)n_in; (void)out_size;

  k0_kernel<<<1, 256, 0, stream>>>(init_w, Wv, hWq, low_init_w, lWv, lWq,
                                   w_hkeys, w_lkeys, w_g0h, w_g0l);
  k_mean<<<2048, 256, 0, stream>>>(node_ctx, w_mnc, 64);
  k_mean<<<64, 256, 0, stream>>>(cell_ctx, w_mcc, 32);

  dim3 g256(16, 4), g2048(128, 4), g64(4, 4);
  k_gemm<<<g256, 256, 0, stream>>>(Wv,            256, nullptr, hWq, nullptr, w_M1h, 256, 256, 256);
  k_gemm<<<g256, 256, 0, stream>>>(Wv + 65536,    256, nullptr, hWq, nullptr, w_Ah,  256, 256, 256);
  k_gemm<<<g256, 256, 0, stream>>>(lWv,           256, nullptr, lWq, nullptr, w_M1l, 256, 256, 256);
  k_gemm<<<g256, 256, 0, stream>>>(lWv + 65536,   256, nullptr, lWq, nullptr, w_Al,  256, 256, 256);
  k_gemm<<<g2048, 256, 0, stream>>>(cell_ctx, 256, nullptr, hWr, hbr, w_rhigh, 2048, 256, 256);
  k_gemm<<<g2048, 256, 0, stream>>>(cell_ctx, 256, nullptr, w_Ah, nullptr, w_Qh, 2048, 256, 256);
  k_gemm<<<g64,   256, 0, stream>>>(w_mcc, 256, nullptr, Wc,  bc,  w_hbh, 64,   256, 256);
  k_gemm<<<g2048, 256, 0, stream>>>(w_mnc, 256, nullptr, lWc, lbc, w_hbl, 2048, 256, 256);
  k_gemm<<<g64,   256, 0, stream>>>(w_hbh, 256, bv,  hWq, hbq, w_hq0h, 64,   256, 256);
  k_gemm<<<g2048, 256, 0, stream>>>(w_hbl, 256, lbv, lWq, lbq, w_hq0l, 2048, 256, 256);

  // r / Q for ALL (b,c) cells — independent of the high-level sampling order
  k_bgemm<<<dim3(1024, 4), 256, 0, stream>>>(node_ctx, lWr, w_Al, lbr, w_R, w_Qm);

  k_high<<<64, 256, 0, stream>>>(cell_ctx, high_mask, hv, w_hq0h, w_g0h, w_Qh,
                                 w_rhigh, w_M1h, w_hkeys, w_hidx, w_hlogp);
  k_lowstep<<<2048, 256, 0, stream>>>(node_ctx, orig, low_mask, lv, w_R, w_Qm,
                                      w_M1l, w_hq0l, w_g0l, w_lkeys, w_hidx,
                                      w_llogp, w_lR, w_lastn, w_initn);
  k_stitch<<<1, 64, 0, stream>>>(w_hlogp, w_llogp, w_lR, w_lastn, w_initn, out);
}

// Round 3
// 2182.656 us; speedup vs baseline: 1.5018x; 1.1049x over previous
//
#include <hip/hip_runtime.h>
#include <cstdint>
#include <cstddef>

#define B_  64
#define NC_ 32
#define NL_ 64
#define E_  256
#define H_  256

// ---------------- Threefry-2x32, 20 rounds (JAX-compatible) ----------------
__device__ __forceinline__ void tf2x32(unsigned k0, unsigned k1,
                                       unsigned c0, unsigned c1,
                                       unsigned &o0, unsigned &o1) {
  unsigned ks2 = k0 ^ k1 ^ 0x1BD11BDAu;
  unsigned x0 = c0 + k0, x1 = c1 + k1;
#define TFR(r) { x0 += x1; x1 = (x1 << r) | (x1 >> (32 - r)); x1 ^= x0; }
  TFR(13) TFR(15) TFR(26) TFR(6)   x0 += k1;  x1 += ks2 + 1u;
  TFR(17) TFR(29) TFR(16) TFR(24)  x0 += ks2; x1 += k0 + 2u;
  TFR(13) TFR(15) TFR(26) TFR(6)   x0 += k0;  x1 += k1 + 3u;
  TFR(17) TFR(29) TFR(16) TFR(24)  x0 += k1;  x1 += ks2 + 4u;
  TFR(13) TFR(15) TFR(26) TFR(6)   x0 += ks2; x1 += k0 + 5u;
#undef TFR
  o0 = x0; o1 = x1;
}

__device__ __forceinline__ float gumbel_bits(unsigned k0, unsigned k1, unsigned flat) {
  unsigned a, b;
  tf2x32(k0, k1, 0u, flat, a, b);
  unsigned bits = a ^ b;
  float f = __uint_as_float(0x3F800000u | (bits >> 9)) - 1.0f;
  f = fmaxf(f, 1.17549435e-38f);
  return -logf(-logf(f));
}

__device__ __forceinline__ float ftanh(float x) {
  return 1.0f - 2.0f / (__expf(2.0f * x) + 1.0f);
}

// ---------------- K0: keys + init vectors ----------------
__global__ __launch_bounds__(256) void k0_kernel(
    const float* __restrict__ init_w, const float* __restrict__ Wv,
    const float* __restrict__ hWq,
    const float* __restrict__ low_init_w, const float* __restrict__ lWv,
    const float* __restrict__ lWq,
    unsigned* __restrict__ hkeys, unsigned* __restrict__ lkeys,
    float* __restrict__ g0h, float* __restrict__ g0l) {
  int tid = threadIdx.x;
  __shared__ float s_iwv[E_], s_liwv[E_];
  if (tid < 32) {
    unsigned a, b;
    tf2x32(0u, 42u, 0u, (unsigned)tid, a, b);
    hkeys[2*tid] = a; hkeys[2*tid+1] = b;
    tf2x32(0u, 7u, 0u, (unsigned)tid, a, b);
    lkeys[2*tid] = a; lkeys[2*tid+1] = b;
  }
  {
    float a = 0.f, a2 = 0.f;
    for (int k = 0; k < 2*E_; ++k) {
      a  = fmaf(init_w[k],     Wv[(size_t)k*E_ + tid], a);
      a2 = fmaf(low_init_w[k], lWv[(size_t)k*E_ + tid], a2);
    }
    s_iwv[tid] = a; s_liwv[tid] = a2;
  }
  __syncthreads();
  {
    float a = 0.f, a2 = 0.f;
    for (int e = 0; e < E_; ++e) {
      a  = fmaf(s_iwv[e],  hWq[(size_t)e*H_ + tid], a);
      a2 = fmaf(s_liwv[e], lWq[(size_t)e*H_ + tid], a2);
    }
    g0h[tid] = a; g0l[tid] = a2;
  }
}

// ---------------- means over middle dim ----------------
__global__ __launch_bounds__(256) void k_mean(const float* __restrict__ in,
                                              float* __restrict__ out, int G) {
  int row = blockIdx.x, h = threadIdx.x;
  const float* p = in + (size_t)row * G * E_ + h;
  float a = 0.f;
  for (int g = 0; g < G; ++g) a += p[(size_t)g * E_];
  out[(size_t)row * E_ + h] = a * (1.0f / G);
}

// ---------------- generic small GEMM: C = (A .+ avec) @ W + bias ----------------
__global__ __launch_bounds__(256) void k_gemm(
    const float* __restrict__ A, int lda, const float* __restrict__ avec,
    const float* __restrict__ W, const float* __restrict__ bias,
    float* __restrict__ C, int M, int N, int K) {
  __shared__ float As[16][17];
  int i0 = blockIdx.x * 16, j0 = blockIdx.y * 64;
  int tx = threadIdx.x & 63, ty = threadIdx.x >> 6;
  int j = j0 + tx;
  float acc[4] = {0.f, 0.f, 0.f, 0.f};
  for (int kk = 0; kk < K; kk += 16) {
    int r = threadIdx.x >> 4, cc = threadIdx.x & 15;
    float av = A[(size_t)(i0 + r) * lda + kk + cc];
    if (avec) av += avec[kk + cc];
    As[r][cc] = av;
    __syncthreads();
#pragma unroll
    for (int kt = 0; kt < 16; ++kt) {
      float w = W[(size_t)(kk + kt) * N + j];
#pragma unroll
      for (int k2 = 0; k2 < 4; ++k2)
        acc[k2] = fmaf(As[ty*4 + k2][kt], w, acc[k2]);
    }
    __syncthreads();
  }
  float bb = bias ? bias[j] : 0.f;
#pragma unroll
  for (int k2 = 0; k2 < 4; ++k2)
    C[(size_t)(i0 + ty*4 + k2) * N + j] = acc[k2] + bb;
}

// ---------------- gathered GEMM: sbase[o] = hq0l[cell_o] + node_ctx[arow_o] @ M1l ----------------
__global__ __launch_bounds__(256) void k_gemmg(
    const float* __restrict__ nodectx, const int* __restrict__ arow,
    const int* __restrict__ cellarr, const float* __restrict__ W,
    const float* __restrict__ hq0l, float* __restrict__ C) {
  __shared__ float As[16][17];
  __shared__ int rows[16];
  int i0 = blockIdx.x * 16, j0 = blockIdx.y * 64;
  int tx = threadIdx.x & 63, ty = threadIdx.x >> 6;
  int j = j0 + tx;
  if (threadIdx.x < 16) rows[threadIdx.x] = arow[i0 + threadIdx.x];
  __syncthreads();
  float acc[4] = {0.f, 0.f, 0.f, 0.f};
  for (int kk = 0; kk < 256; kk += 16) {
    int r = threadIdx.x >> 4, cc = threadIdx.x & 15;
    As[r][cc] = nodectx[(size_t)rows[r] * 256 + kk + cc];
    __syncthreads();
#pragma unroll
    for (int kt = 0; kt < 16; ++kt) {
      float w = W[(size_t)(kk + kt) * 256 + j];
#pragma unroll
      for (int k2 = 0; k2 < 4; ++k2)
        acc[k2] = fmaf(As[ty*4 + k2][kt], w, acc[k2]);
    }
    __syncthreads();
  }
#pragma unroll
  for (int k2 = 0; k2 < 4; ++k2) {
    int row = i0 + ty*4 + k2;
    C[(size_t)row * 256 + j] = acc[k2] + hq0l[(size_t)cellarr[row] * 256 + j];
  }
}

// ---------------- big GEMM: [R|Q] = node_ctx(131072x256) @ [lWr | Al](256x512) ----------------
__global__ __launch_bounds__(256, 2) void k_bgemm(
    const float* __restrict__ A, const float* __restrict__ Wr,
    const float* __restrict__ Alm, const float* __restrict__ lbr,
    float* __restrict__ Rout, float* __restrict__ Qout) {
  __shared__ float As[16][132];
  __shared__ float Ws[16][132];
  int bx = blockIdx.x, by = blockIdx.y;
  const float* Wbase = (by < 2) ? Wr : Alm;
  float* Cbase = (by < 2) ? Rout : Qout;
  int jb = (by & 1) * 128;
  bool doBias = (by < 2);
  int m0 = bx * 128;
  int tid = threadIdx.x;
  int tx = tid & 15, ty = tid >> 4;
  float acc[8][8];
#pragma unroll
  for (int i = 0; i < 8; ++i)
#pragma unroll
    for (int j = 0; j < 8; ++j) acc[i][j] = 0.f;

  for (int kc = 0; kc < 256; kc += 16) {
    {
      int kq = (tid & 3) * 4;
#pragma unroll
      for (int p = 0; p < 2; ++p) {
        int m = (tid >> 2) + p * 64;
        float4 a4 = *(const float4*)&A[(size_t)(m0 + m) * 256 + kc + kq];
        As[kq + 0][m] = a4.x; As[kq + 1][m] = a4.y;
        As[kq + 2][m] = a4.z; As[kq + 3][m] = a4.w;
      }
      int k = tid >> 4;
      int c4 = (tid & 15) * 8;
      float4 w0 = *(const float4*)&Wbase[(size_t)(kc + k) * 256 + jb + c4];
      float4 w1 = *(const float4*)&Wbase[(size_t)(kc + k) * 256 + jb + c4 + 4];
      *(float4*)&Ws[k][c4] = w0;
      *(float4*)&Ws[k][c4 + 4] = w1;
    }
    __syncthreads();
#pragma unroll
    for (int k = 0; k < 16; ++k) {
      float4 a0 = *(float4*)&As[k][ty * 8];
      float4 a1 = *(float4*)&As[k][ty * 8 + 4];
      float4 w0 = *(float4*)&Ws[k][tx * 8];
      float4 w1 = *(float4*)&Ws[k][tx * 8 + 4];
      float av[8] = {a0.x, a0.y, a0.z, a0.w, a1.x, a1.y, a1.z, a1.w};
      float wv[8] = {w0.x, w0.y, w0.z, w0.w, w1.x, w1.y, w1.z, w1.w};
#pragma unroll
      for (int i = 0; i < 8; ++i)
#pragma unroll
        for (int j = 0; j < 8; ++j)
          acc[i][j] = fmaf(av[i], wv[j], acc[i][j]);
    }
    __syncthreads();
  }
  float bias[8];
#pragma unroll
  for (int j = 0; j < 8; ++j)
    bias[j] = doBias ? lbr[jb + tx * 8 + j] : 0.f;
#pragma unroll
  for (int i = 0; i < 8; ++i) {
    float4 o0 = make_float4(acc[i][0] + bias[0], acc[i][1] + bias[1],
                            acc[i][2] + bias[2], acc[i][3] + bias[3]);
    float4 o1 = make_float4(acc[i][4] + bias[4], acc[i][5] + bias[5],
                            acc[i][6] + bias[6], acc[i][7] + bias[7]);
    size_t base = (size_t)(m0 + ty * 8 + i) * 256 + jb + tx * 8;
    *(float4*)&Cbase[base] = o0;
    *(float4*)&Cbase[base + 4] = o1;
  }
}

// ---------------- u0 for all cells: u0[cell][n] = 10 tanh(sum lv*tanh(hq0l+g0l+r)) ----------------
__global__ __launch_bounds__(256) void k_u0k(
    const float* __restrict__ R, const float* __restrict__ hq0l,
    const float* __restrict__ g0l, const float* __restrict__ lv,
    float* __restrict__ u0) {
  int cell = blockIdx.x, tid = threadIdx.x, lane = tid & 63, w = tid >> 6;
  __shared__ float qs[256];
  qs[tid] = hq0l[(size_t)cell*256 + tid] + g0l[tid];
  __syncthreads();
  float lvr[4], qsr[4];
#pragma unroll
  for (int q = 0; q < 4; ++q) { lvr[q] = lv[lane + 64*q]; qsr[q] = qs[lane + 64*q]; }
  const float* Rb = R + (size_t)cell * 16384;
  for (int i = 0; i < 16; ++i) {
    int n = w*16 + i;
    const float* rr = Rb + (size_t)n*256;
    float a = 0.f;
#pragma unroll
    for (int q = 0; q < 4; ++q)
      a = fmaf(lvr[q], ftanh(qsr[q] + rr[lane + 64*q]), a);
#pragma unroll
    for (int off = 32; off; off >>= 1) a += __shfl_xor(a, off);
    if (lane == 0) u0[(size_t)cell*64 + n] = 10.0f * ftanh(a);
  }
}

// ---------------- phase A: high-level sampling chain ----------------
__global__ __launch_bounds__(256) void k_high(
    const float* __restrict__ cell_ctx, const int* __restrict__ high_mask,
    const float* __restrict__ hv,
    const float* __restrict__ ws_hq0h, const float* __restrict__ ws_g0h,
    const float* __restrict__ ws_Qh, const float* __restrict__ ws_rhigh,
    const float* __restrict__ ws_M1h, const unsigned* __restrict__ ws_hkeys,
    int* __restrict__ ws_hidx, float* __restrict__ ws_hlogp) {
  int b = blockIdx.x, tid = threadIdx.x;
  int lane = tid & 63, w = tid >> 6;
  __shared__ float s[H_], addM[H_], hq0[H_], g0[H_], hvv[H_];
  __shared__ float uarr[NC_];
  __shared__ int prev_s;
  __shared__ unsigned hm_s;
  __shared__ float acc_s;
  hq0[tid] = ws_hq0h[(size_t)b*H_ + tid];
  g0[tid] = ws_g0h[tid];
  hvv[tid] = hv[tid];
  if (tid == 0) {
    unsigned m = 0;
    for (int c = 0; c < NC_; ++c) if (high_mask[b*NC_ + c] > 0) m |= (1u << c);
    hm_s = m; acc_s = 0.f; prev_s = 0;
  }
  __syncthreads();
  for (int t = 0; t < NC_; ++t) {
    {
      float v = hq0[tid];
      if (t == 0) v += g0[tid];
      else        v += addM[tid] + ws_Qh[(size_t)(b*NC_ + prev_s)*H_ + tid];
      s[tid] = v;
    }
    __syncthreads();
    unsigned hm = hm_s;
    for (int q8 = 0; q8 < 8; ++q8) {
      int cidx = w*8 + q8;
      if ((hm >> cidx) & 1u) continue;
      const float* rr = ws_rhigh + (size_t)(b*NC_ + cidx)*H_;
      float a = 0.f;
#pragma unroll
      for (int jj = 0; jj < 4; ++jj) {
        int h = lane + 64*jj;
        a += hvv[h] * ftanh(s[h] + rr[h]);
      }
#pragma unroll
      for (int off = 32; off; off >>= 1) a += __shfl_xor(a, off);
      if (lane == 0) uarr[cidx] = 10.0f * ftanh(a);
    }
    __syncthreads();
    if (w == 0) {
      int cidx = lane;
      bool valid = (cidx < NC_);
      bool masked = valid && ((hm >> cidx) & 1u);
      float logit = valid ? (masked ? -1e9f : uarr[cidx]) : -INFINITY;
      float val = -INFINITY;
      if (valid) {
        float g = gumbel_bits(ws_hkeys[2*t], ws_hkeys[2*t+1],
                              (unsigned)(b*NC_ + cidx));
        val = logit + g;
      }
      float bvv = val; int bi = valid ? cidx : 9999;
#pragma unroll
      for (int off = 32; off; off >>= 1) {
        float ov = __shfl_xor(bvv, off); int oi = __shfl_xor(bi, off);
        if (ov > bvv || (ov == bvv && oi < bi)) { bvv = ov; bi = oi; }
      }
      float m = logit;
#pragma unroll
      for (int off = 32; off; off >>= 1) m = fmaxf(m, __shfl_xor(m, off));
      float ex = (valid && !masked) ? expf(logit - m) : 0.f;
#pragma unroll
      for (int off = 32; off; off >>= 1) ex += __shfl_xor(ex, off);
      float lsel = __shfl(logit, bi);
      float logp = lsel - m - logf(ex);
      if (lane == 0) {
        acc_s += logp;
        ws_hidx[b*NC_ + t] = bi;
        hm_s = hm | (1u << bi);
        prev_s = bi;
      }
    }
    __syncthreads();
    if (t == 0) {
      {
        int idx0 = prev_s;
        const float* crow = cell_ctx + (size_t)(b*NC_ + idx0)*E_;
        float a = 0.f;
        for (int e = 0; e < E_; ++e)
          a = fmaf(crow[e], ws_M1h[(size_t)e*H_ + tid], a);
        addM[tid] = a;
      }
      __syncthreads();
    }
  }
  if (tid == 0) ws_hlogp[b] = acc_s;
}

// ---------------- idx0 sampling (step 0) per (b,t) ----------------
__global__ __launch_bounds__(256) void k_idx0(
    const int* __restrict__ low_mask, const unsigned* __restrict__ lkeys,
    const int* __restrict__ hidx, const float* __restrict__ u0,
    int* __restrict__ arow, int* __restrict__ cellarr) {
  int tid = threadIdx.x, lane = tid & 63, w = tid >> 6;
  int o = blockIdx.x * 4 + w;
  int b = o >> 5, t = o & 31;
  int c = hidx[o], cell = b*NC_ + c;
  float logit = (low_mask[(size_t)cell*64 + lane] > 0) ? -1e9f
               : u0[(size_t)cell*64 + lane];
  unsigned s0, s1;
  tf2x32(lkeys[2*t], lkeys[2*t+1], 0u, 0u, s0, s1);
  float g = gumbel_bits(s0, s1, (unsigned)(b*NL_ + lane));
  float val = logit + g;
  float bvv = val; int bi = lane;
#pragma unroll
  for (int off = 32; off; off >>= 1) {
    float ov = __shfl_xor(bvv, off); int oi = __shfl_xor(bi, off);
    if (ov > bvv || (ov == bvv && oi < bi)) { bvv = ov; bi = oi; }
  }
  if (lane == 0) { arow[o] = cell*64 + bi; cellarr[o] = cell; }
}

// ---------------- U table: U[o][j][n] = 10 tanh(sum_h lv tanh(sbase+Q[j]+r[n])) ----------------
__global__ __launch_bounds__(512, 6) void k_utab(
    const float* __restrict__ R, const float* __restrict__ Qm,
    const float* __restrict__ sbase, const float* __restrict__ lv,
    const int* __restrict__ hidx, float* __restrict__ U) {
  __shared__ float r_lds[32 * 260];     // 32 rows, padded stride
  __shared__ float qrow[8][264];        // per-wave staged sbase+Q[j]
  __shared__ float lvs[256];
  int tid = threadIdx.x, lane = tid & 63, w = tid >> 6;
  int o = blockIdx.x, b = o >> 5, t = o & 31;
  int c = hidx[o], cell = b*NC_ + c;
  const float* Rb = R + (size_t)cell * 16384;
  const float* Qb = Qm + (size_t)cell * 16384;
  if (tid < 64) *(float4*)&lvs[4*tid] = *(const float4*)&lv[4*tid];
  float4 sb4 = *(const float4*)&sbase[(size_t)o*256 + 4*lane];
  int rbase = (lane >> 5) * 128;        // h-half this lane covers
  int nloc = lane & 31;                 // local row index
  float* qw = qrow[w];
  for (int p = 0; p < 2; ++p) {
    if (p) __syncthreads();             // protect pass-0 reads
    // stage rows p*32 .. p*32+31 (fully coalesced per wave)
#pragma unroll
    for (int k = 0; k < 4; ++k) {
      int f = tid + 512*k;              // float4 index within 32x256
      int nl = f >> 6, h4 = (f & 63) * 4;
      float4 v = *(const float4*)&Rb[(size_t)(p*32 + nl)*256 + h4];
      *(float4*)&r_lds[nl*260 + h4] = v;
    }
    __syncthreads();
    for (int jj = 0; jj < 8; ++jj) {
      int j = w*8 + jj;
      {
        float4 q4 = *(const float4*)&Qb[(size_t)j*256 + 4*lane];
        *(float4*)&qw[4*lane] = make_float4(sb4.x + q4.x, sb4.y + q4.y,
                                            sb4.z + q4.z, sb4.w + q4.w);
      }
      float4 acc = make_float4(0.f, 0.f, 0.f, 0.f);
#pragma unroll 8
      for (int cc = 0; cc < 32; ++cc) {
        int hh = rbase + 4*cc;
        float4 qv = *(float4*)&qw[hh];
        float4 l4 = *(float4*)&lvs[hh];
        float4 rv = *(float4*)&r_lds[nloc*260 + hh];
        acc.x = fmaf(l4.x, ftanh(qv.x + rv.x), acc.x);
        acc.y = fmaf(l4.y, ftanh(qv.y + rv.y), acc.y);
        acc.z = fmaf(l4.z, ftanh(qv.z + rv.z), acc.z);
        acc.w = fmaf(l4.w, ftanh(qv.w + rv.w), acc.w);
      }
      float a = (acc.x + acc.y) + (acc.z + acc.w);
      a += __shfl_xor(a, 32);
      if (lane < 32)
        U[(size_t)o*4096 + j*64 + p*32 + lane] = 10.0f * ftanh(a);
    }
  }
}

// ---------------- sequential low sampler: one wave per (b,t) ----------------
__global__ __launch_bounds__(256) void k_lowseq(
    const float* __restrict__ orig, const int* __restrict__ low_mask,
    const unsigned* __restrict__ lkeys, const int* __restrict__ hidx,
    const float* __restrict__ u0, const float* __restrict__ U,
    float* __restrict__ llogp, float* __restrict__ lRr,
    float* __restrict__ lastn, float* __restrict__ initn) {
  int tid = threadIdx.x, lane = tid & 63, w = tid >> 6;
  int o = blockIdx.x * 4 + w;
  int b = o >> 5, t = o & 31;
  int c = hidx[o], cell = b*NC_ + c;
  float cx = orig[(size_t)cell*128 + 2*lane];
  float cy = orig[(size_t)cell*128 + 2*lane + 1];
  int maskb = (low_mask[(size_t)cell*64 + lane] > 0) ? 1 : 0;
  unsigned sk0, sk1;
  tf2x32(lkeys[2*t], lkeys[2*t+1], 0u, (unsigned)lane, sk0, sk1);
  float row = u0[(size_t)cell*64 + lane];
  float px = __shfl(cx, 0), py = __shfl(cy, 0);
  float ix = px, iy = py;
  float lp = 0.f, rw = 0.f;
  const float* Ub = U + (size_t)o * 4096;
  for (int s = 0; s < NL_; ++s) {
    float logit = maskb ? -1e9f : row;
    unsigned k0 = (unsigned)__shfl((int)sk0, s);
    unsigned k1 = (unsigned)__shfl((int)sk1, s);
    float g = gumbel_bits(k0, k1, (unsigned)(b*NL_ + lane));
    float val = logit + g;
    float bvv = val; int bi = lane;
#pragma unroll
    for (int off = 32; off; off >>= 1) {
      float ov = __shfl_xor(bvv, off); int oi = __shfl_xor(bi, off);
      if (ov > bvv || (ov == bvv && oi < bi)) { bvv = ov; bi = oi; }
    }
    // prefetch next logits row while softmax completes
    float nrow = Ub[(size_t)bi*64 + lane];
    float m = logit;
#pragma unroll
    for (int off = 32; off; off >>= 1) m = fmaxf(m, __shfl_xor(m, off));
    float ex = maskb ? 0.f : expf(logit - m);
#pragma unroll
    for (int off = 32; off; off >>= 1) ex += __shfl_xor(ex, off);
    float lsel = __shfl(logit, bi);
    lp += lsel - m - logf(ex);
    float bx = __shfl(cx, bi), by = __shfl(cy, bi);
    float dx = bx - px, dy = by - py;
    rw += sqrtf(dx*dx + dy*dy + 1e-12f);
    px = bx; py = by;
    if (lane == bi) maskb = 1;
    row = nrow;
  }
  if (lane == 0) {
    llogp[o] = lp; lRr[o] = rw;
    lastn[2*o] = px; lastn[2*o+1] = py;
    initn[2*o] = ix; initn[2*o+1] = iy;
  }
}

// ---------------- phase C: stitch ----------------
__global__ __launch_bounds__(64) void k_stitch(
    const float* __restrict__ ws_hlogp, const float* __restrict__ ws_llogp,
    const float* __restrict__ ws_lR, const float* __restrict__ ws_lastn,
    const float* __restrict__ ws_initn, float* __restrict__ out) {
  int b = threadIdx.x;
  if (b >= B_) return;
  float lp = ws_hlogp[b], rw = 0.f, lx = 0.f, ly = 0.f;
  for (int t = 0; t < NC_; ++t) {
    int o = b*NC_ + t;
    lp += ws_llogp[o];
    float dx = ws_initn[2*o] - lx, dy = ws_initn[2*o+1] - ly;
    rw += ws_lR[o] + sqrtf(dx*dx + dy*dy + 1e-12f);
    lx = ws_lastn[2*o]; ly = ws_lastn[2*o+1];
  }
  out[b] = lp;
  out[B_ + b] = rw;
}

// ---------------- host launcher ----------------
extern "C" void kernel_launch(void* const* d_in, const int* in_sizes, int n_in,
                              void* d_out, int out_size, void* d_ws, size_t ws_size,
                              hipStream_t stream) {
  const float* node_ctx  = (const float*)d_in[0];
  const float* cell_ctx  = (const float*)d_in[1];
  const float* orig      = (const float*)d_in[2];
  const int*   high_mask = (const int*)d_in[3];
  const int*   low_mask  = (const int*)d_in[4];
  const float* init_w    = (const float*)d_in[5];
  const float* Wc        = (const float*)d_in[6];
  const float* bc        = (const float*)d_in[7];
  const float* Wv        = (const float*)d_in[8];
  const float* bv        = (const float*)d_in[9];
  const float* hWq       = (const float*)d_in[10];
  const float* hbq       = (const float*)d_in[11];
  const float* hWr       = (const float*)d_in[12];
  const float* hbr       = (const float*)d_in[13];
  const float* hv        = (const float*)d_in[14];
  const float* low_init_w= (const float*)d_in[15];
  const float* lWc       = (const float*)d_in[16];
  const float* lbc       = (const float*)d_in[17];
  const float* lWv       = (const float*)d_in[18];
  const float* lbv       = (const float*)d_in[19];
  const float* lWq       = (const float*)d_in[20];
  const float* lbq       = (const float*)d_in[21];
  const float* lWr       = (const float*)d_in[22];
  const float* lbr       = (const float*)d_in[23];
  const float* lv        = (const float*)d_in[24];
  float* out = (float*)d_out;

  char* ws = (char*)d_ws;
  size_t off = 0;
  auto alloc = [&](size_t bytes) -> void* {
    void* p = ws + off;
    off += (bytes + 255) & ~(size_t)255;
    return p;
  };
  unsigned* w_hkeys = (unsigned*)alloc(32*2*4);
  unsigned* w_lkeys = (unsigned*)alloc(32*2*4);
  int*   w_hidx  = (int*)alloc(2048*4);
  int*   w_arow  = (int*)alloc(2048*4);
  int*   w_cell  = (int*)alloc(2048*4);
  float* w_hlogp = (float*)alloc(64*4);
  float* w_llogp = (float*)alloc(2048*4);
  float* w_lR    = (float*)alloc(2048*4);
  float* w_lastn = (float*)alloc(2048*2*4);
  float* w_initn = (float*)alloc(2048*2*4);
  float* w_g0h   = (float*)alloc(256*4);
  float* w_g0l   = (float*)alloc(256*4);
  float* w_M1h   = (float*)alloc((size_t)65536*4);
  float* w_Ah    = (float*)alloc((size_t)65536*4);
  float* w_M1l   = (float*)alloc((size_t)65536*4);
  float* w_Al    = (float*)alloc((size_t)65536*4);
  float* w_mcc   = (float*)alloc((size_t)64*256*4);
  float* w_mnc   = (float*)alloc((size_t)2048*256*4);
  float* w_hbh   = (float*)alloc((size_t)64*256*4);
  float* w_hq0h  = (float*)alloc((size_t)64*256*4);
  float* w_rhigh = (float*)alloc((size_t)2048*256*4);
  float* w_Qh    = (float*)alloc((size_t)2048*256*4);
  float* w_hbl   = (float*)alloc((size_t)2048*256*4);
  float* w_hq0l  = (float*)alloc((size_t)2048*256*4);
  float* w_u0    = (float*)alloc((size_t)2048*64*4);
  float* w_sbase = (float*)alloc((size_t)2048*256*4);
  float* w_U     = (float*)alloc((size_t)2048*4096*4);     // 33.5 MB
  float* w_R     = (float*)alloc((size_t)2048*64*256*4);   // 134 MB
  float* w_Qm    = (float*)alloc((size_t)2048*64*256*4);   // 134 MB
  (void)ws_size; (void)in_sizes; (void)n_in; (void)out_size;

  k0_kernel<<<1, 256, 0, stream>>>(init_w, Wv, hWq, low_init_w, lWv, lWq,
                                   w_hkeys, w_lkeys, w_g0h, w_g0l);
  k_mean<<<2048, 256, 0, stream>>>(node_ctx, w_mnc, 64);
  k_mean<<<64, 256, 0, stream>>>(cell_ctx, w_mcc, 32);

  dim3 g256(16, 4), g2048(128, 4), g64(4, 4);
  k_gemm<<<g256, 256, 0, stream>>>(Wv,            256, nullptr, hWq, nullptr, w_M1h, 256, 256, 256);
  k_gemm<<<g256, 256, 0, stream>>>(Wv + 65536,    256, nullptr, hWq, nullptr, w_Ah,  256, 256, 256);
  k_gemm<<<g256, 256, 0, stream>>>(lWv,           256, nullptr, lWq, nullptr, w_M1l, 256, 256, 256);
  k_gemm<<<g256, 256, 0, stream>>>(lWv + 65536,   256, nullptr, lWq, nullptr, w_Al,  256, 256, 256);
  k_gemm<<<g2048, 256, 0, stream>>>(cell_ctx, 256, nullptr, hWr, hbr, w_rhigh, 2048, 256, 256);
  k_gemm<<<g2048, 256, 0, stream>>>(cell_ctx, 256, nullptr, w_Ah, nullptr, w_Qh, 2048, 256, 256);
  k_gemm<<<g64,   256, 0, stream>>>(w_mcc, 256, nullptr, Wc,  bc,  w_hbh, 64,   256, 256);
  k_gemm<<<g2048, 256, 0, stream>>>(w_mnc, 256, nullptr, lWc, lbc, w_hbl, 2048, 256, 256);
  k_gemm<<<g64,   256, 0, stream>>>(w_hbh, 256, bv,  hWq, hbq, w_hq0h, 64,   256, 256);
  k_gemm<<<g2048, 256, 0, stream>>>(w_hbl, 256, lbv, lWq, lbq, w_hq0l, 2048, 256, 256);

  k_bgemm<<<dim3(1024, 4), 256, 0, stream>>>(node_ctx, lWr, w_Al, lbr, w_R, w_Qm);
  k_u0k<<<2048, 256, 0, stream>>>(w_R, w_hq0l, w_g0l, lv, w_u0);

  k_high<<<64, 256, 0, stream>>>(cell_ctx, high_mask, hv, w_hq0h, w_g0h, w_Qh,
                                 w_rhigh, w_M1h, w_hkeys, w_hidx, w_hlogp);
  k_idx0<<<512, 256, 0, stream>>>(low_mask, w_lkeys, w_hidx, w_u0, w_arow, w_cell);
  k_gemmg<<<dim3(128, 4), 256, 0, stream>>>(node_ctx, w_arow, w_cell, w_M1l,
                                            w_hq0l, w_sbase);
  k_utab<<<2048, 512, 0, stream>>>(w_R, w_Qm, w_sbase, lv, w_hidx, w_U);
  k_lowseq<<<512, 256, 0, stream>>>(orig, low_mask, w_lkeys, w_hidx, w_u0, w_U,
                                    w_llogp, w_lR, w_lastn, w_initn);
  k_stitch<<<1, 64, 0, stream>>>(w_hlogp, w_llogp, w_lR, w_lastn, w_initn, out);
}

// Round 4
// 1939.915 us; speedup vs baseline: 1.6897x; 1.1251x over previous
//
#include <hip/hip_runtime.h>
#include <cstdint>
#include <cstddef>

#define B_  64
#define NC_ 32
#define NL_ 64
#define E_  256
#define H_  256

// ---------------- Threefry-2x32, 20 rounds (JAX-compatible) ----------------
__device__ __forceinline__ void tf2x32(unsigned k0, unsigned k1,
                                       unsigned c0, unsigned c1,
                                       unsigned &o0, unsigned &o1) {
  unsigned ks2 = k0 ^ k1 ^ 0x1BD11BDAu;
  unsigned x0 = c0 + k0, x1 = c1 + k1;
#define TFR(r) { x0 += x1; x1 = (x1 << r) | (x1 >> (32 - r)); x1 ^= x0; }
  TFR(13) TFR(15) TFR(26) TFR(6)   x0 += k1;  x1 += ks2 + 1u;
  TFR(17) TFR(29) TFR(16) TFR(24)  x0 += ks2; x1 += k0 + 2u;
  TFR(13) TFR(15) TFR(26) TFR(6)   x0 += k0;  x1 += k1 + 3u;
  TFR(17) TFR(29) TFR(16) TFR(24)  x0 += k1;  x1 += ks2 + 4u;
  TFR(13) TFR(15) TFR(26) TFR(6)   x0 += ks2; x1 += k0 + 5u;
#undef TFR
  o0 = x0; o1 = x1;
}

__device__ __forceinline__ float gumbel_bits(unsigned k0, unsigned k1, unsigned flat) {
  unsigned a, b;
  tf2x32(k0, k1, 0u, flat, a, b);
  unsigned bits = a ^ b;
  float f = __uint_as_float(0x3F800000u | (bits >> 9)) - 1.0f;
  f = fmaxf(f, 1.17549435e-38f);
  return -logf(-logf(f));
}

// tanh via native exp + native rcp (no IEEE divide sequence).
__device__ __forceinline__ float ftanh(float x) {
  float e = __expf(2.0f * x);
  return fmaf(-2.0f, __builtin_amdgcn_rcpf(e + 1.0f), 1.0f);
}
// tanh given pre-doubled argument (x2 == 2*x exactly).
__device__ __forceinline__ float ftanh2(float x2) {
  float e = __expf(x2);
  return fmaf(-2.0f, __builtin_amdgcn_rcpf(e + 1.0f), 1.0f);
}

// ---------------- K0: keys + init vectors ----------------
__global__ __launch_bounds__(256) void k0_kernel(
    const float* __restrict__ init_w, const float* __restrict__ Wv,
    const float* __restrict__ hWq,
    const float* __restrict__ low_init_w, const float* __restrict__ lWv,
    const float* __restrict__ lWq,
    unsigned* __restrict__ hkeys, unsigned* __restrict__ lkeys,
    float* __restrict__ g0h, float* __restrict__ g0l) {
  int tid = threadIdx.x;
  __shared__ float s_iwv[E_], s_liwv[E_];
  if (tid < 32) {
    unsigned a, b;
    tf2x32(0u, 42u, 0u, (unsigned)tid, a, b);
    hkeys[2*tid] = a; hkeys[2*tid+1] = b;
    tf2x32(0u, 7u, 0u, (unsigned)tid, a, b);
    lkeys[2*tid] = a; lkeys[2*tid+1] = b;
  }
  {
    float a = 0.f, a2 = 0.f;
    for (int k = 0; k < 2*E_; ++k) {
      a  = fmaf(init_w[k],     Wv[(size_t)k*E_ + tid], a);
      a2 = fmaf(low_init_w[k], lWv[(size_t)k*E_ + tid], a2);
    }
    s_iwv[tid] = a; s_liwv[tid] = a2;
  }
  __syncthreads();
  {
    float a = 0.f, a2 = 0.f;
    for (int e = 0; e < E_; ++e) {
      a  = fmaf(s_iwv[e],  hWq[(size_t)e*H_ + tid], a);
      a2 = fmaf(s_liwv[e], lWq[(size_t)e*H_ + tid], a2);
    }
    g0h[tid] = a; g0l[tid] = a2;
  }
}

// ---------------- means over middle dim ----------------
__global__ __launch_bounds__(256) void k_mean(const float* __restrict__ in,
                                              float* __restrict__ out, int G) {
  int row = blockIdx.x, h = threadIdx.x;
  const float* p = in + (size_t)row * G * E_ + h;
  float a = 0.f;
  for (int g = 0; g < G; ++g) a += p[(size_t)g * E_];
  out[(size_t)row * E_ + h] = a * (1.0f / G);
}

// ---------------- generic small GEMM: C = (A .+ avec) @ W + bias ----------------
__global__ __launch_bounds__(256) void k_gemm(
    const float* __restrict__ A, int lda, const float* __restrict__ avec,
    const float* __restrict__ W, const float* __restrict__ bias,
    float* __restrict__ C, int M, int N, int K) {
  __shared__ float As[16][17];
  int i0 = blockIdx.x * 16, j0 = blockIdx.y * 64;
  int tx = threadIdx.x & 63, ty = threadIdx.x >> 6;
  int j = j0 + tx;
  float acc[4] = {0.f, 0.f, 0.f, 0.f};
  for (int kk = 0; kk < K; kk += 16) {
    int r = threadIdx.x >> 4, cc = threadIdx.x & 15;
    float av = A[(size_t)(i0 + r) * lda + kk + cc];
    if (avec) av += avec[kk + cc];
    As[r][cc] = av;
    __syncthreads();
#pragma unroll
    for (int kt = 0; kt < 16; ++kt) {
      float w = W[(size_t)(kk + kt) * N + j];
#pragma unroll
      for (int k2 = 0; k2 < 4; ++k2)
        acc[k2] = fmaf(As[ty*4 + k2][kt], w, acc[k2]);
    }
    __syncthreads();
  }
  float bb = bias ? bias[j] : 0.f;
#pragma unroll
  for (int k2 = 0; k2 < 4; ++k2)
    C[(size_t)(i0 + ty*4 + k2) * N + j] = acc[k2] + bb;
}

// ---------------- gathered GEMM: sbase[o] = hq0l[cell_o] + node_ctx[arow_o] @ M1l ----------------
__global__ __launch_bounds__(256) void k_gemmg(
    const float* __restrict__ nodectx, const int* __restrict__ arow,
    const int* __restrict__ cellarr, const float* __restrict__ W,
    const float* __restrict__ hq0l, float* __restrict__ C) {
  __shared__ float As[16][17];
  __shared__ int rows[16];
  int i0 = blockIdx.x * 16, j0 = blockIdx.y * 64;
  int tx = threadIdx.x & 63, ty = threadIdx.x >> 6;
  int j = j0 + tx;
  if (threadIdx.x < 16) rows[threadIdx.x] = arow[i0 + threadIdx.x];
  __syncthreads();
  float acc[4] = {0.f, 0.f, 0.f, 0.f};
  for (int kk = 0; kk < 256; kk += 16) {
    int r = threadIdx.x >> 4, cc = threadIdx.x & 15;
    As[r][cc] = nodectx[(size_t)rows[r] * 256 + kk + cc];
    __syncthreads();
#pragma unroll
    for (int kt = 0; kt < 16; ++kt) {
      float w = W[(size_t)(kk + kt) * 256 + j];
#pragma unroll
      for (int k2 = 0; k2 < 4; ++k2)
        acc[k2] = fmaf(As[ty*4 + k2][kt], w, acc[k2]);
    }
    __syncthreads();
  }
#pragma unroll
  for (int k2 = 0; k2 < 4; ++k2) {
    int row = i0 + ty*4 + k2;
    C[(size_t)row * 256 + j] = acc[k2] + hq0l[(size_t)cellarr[row] * 256 + j];
  }
}

// ---------------- big GEMM: [R|Q] = node_ctx(131072x256) @ [lWr | Al](256x512) ----------------
__global__ __launch_bounds__(256, 2) void k_bgemm(
    const float* __restrict__ A, const float* __restrict__ Wr,
    const float* __restrict__ Alm, const float* __restrict__ lbr,
    float* __restrict__ Rout, float* __restrict__ Qout) {
  __shared__ float As[16][132];
  __shared__ float Ws[16][132];
  int bx = blockIdx.x, by = blockIdx.y;
  const float* Wbase = (by < 2) ? Wr : Alm;
  float* Cbase = (by < 2) ? Rout : Qout;
  int jb = (by & 1) * 128;
  bool doBias = (by < 2);
  int m0 = bx * 128;
  int tid = threadIdx.x;
  int tx = tid & 15, ty = tid >> 4;
  float acc[8][8];
#pragma unroll
  for (int i = 0; i < 8; ++i)
#pragma unroll
    for (int j = 0; j < 8; ++j) acc[i][j] = 0.f;

  for (int kc = 0; kc < 256; kc += 16) {
    {
      int kq = (tid & 3) * 4;
#pragma unroll
      for (int p = 0; p < 2; ++p) {
        int m = (tid >> 2) + p * 64;
        float4 a4 = *(const float4*)&A[(size_t)(m0 + m) * 256 + kc + kq];
        As[kq + 0][m] = a4.x; As[kq + 1][m] = a4.y;
        As[kq + 2][m] = a4.z; As[kq + 3][m] = a4.w;
      }
      int k = tid >> 4;
      int c4 = (tid & 15) * 8;
      float4 w0 = *(const float4*)&Wbase[(size_t)(kc + k) * 256 + jb + c4];
      float4 w1 = *(const float4*)&Wbase[(size_t)(kc + k) * 256 + jb + c4 + 4];
      *(float4*)&Ws[k][c4] = w0;
      *(float4*)&Ws[k][c4 + 4] = w1;
    }
    __syncthreads();
#pragma unroll
    for (int k = 0; k < 16; ++k) {
      float4 a0 = *(float4*)&As[k][ty * 8];
      float4 a1 = *(float4*)&As[k][ty * 8 + 4];
      float4 w0 = *(float4*)&Ws[k][tx * 8];
      float4 w1 = *(float4*)&Ws[k][tx * 8 + 4];
      float av[8] = {a0.x, a0.y, a0.z, a0.w, a1.x, a1.y, a1.z, a1.w};
      float wv[8] = {w0.x, w0.y, w0.z, w0.w, w1.x, w1.y, w1.z, w1.w};
#pragma unroll
      for (int i = 0; i < 8; ++i)
#pragma unroll
        for (int j = 0; j < 8; ++j)
          acc[i][j] = fmaf(av[i], wv[j], acc[i][j]);
    }
    __syncthreads();
  }
  float bias[8];
#pragma unroll
  for (int j = 0; j < 8; ++j)
    bias[j] = doBias ? lbr[jb + tx * 8 + j] : 0.f;
#pragma unroll
  for (int i = 0; i < 8; ++i) {
    float4 o0 = make_float4(acc[i][0] + bias[0], acc[i][1] + bias[1],
                            acc[i][2] + bias[2], acc[i][3] + bias[3]);
    float4 o1 = make_float4(acc[i][4] + bias[4], acc[i][5] + bias[5],
                            acc[i][6] + bias[6], acc[i][7] + bias[7]);
    size_t base = (size_t)(m0 + ty * 8 + i) * 256 + jb + tx * 8;
    *(float4*)&Cbase[base] = o0;
    *(float4*)&Cbase[base + 4] = o1;
  }
}

// ---------------- u0 for all cells ----------------
__global__ __launch_bounds__(256) void k_u0k(
    const float* __restrict__ R, const float* __restrict__ hq0l,
    const float* __restrict__ g0l, const float* __restrict__ lv,
    float* __restrict__ u0) {
  int cell = blockIdx.x, tid = threadIdx.x, lane = tid & 63, w = tid >> 6;
  __shared__ float qs[256];
  qs[tid] = hq0l[(size_t)cell*256 + tid] + g0l[tid];
  __syncthreads();
  float lvr[4], qsr[4];
#pragma unroll
  for (int q = 0; q < 4; ++q) { lvr[q] = lv[lane + 64*q]; qsr[q] = qs[lane + 64*q]; }
  const float* Rb = R + (size_t)cell * 16384;
  for (int i = 0; i < 16; ++i) {
    int n = w*16 + i;
    const float* rr = Rb + (size_t)n*256;
    float a = 0.f;
#pragma unroll
    for (int q = 0; q < 4; ++q)
      a = fmaf(lvr[q], ftanh(qsr[q] + rr[lane + 64*q]), a);
#pragma unroll
    for (int off = 32; off; off >>= 1) a += __shfl_xor(a, off);
    if (lane == 0) u0[(size_t)cell*64 + n] = 10.0f * ftanh(a);
  }
}

// ---------------- phase A: high-level sampling chain ----------------
__global__ __launch_bounds__(256) void k_high(
    const float* __restrict__ cell_ctx, const int* __restrict__ high_mask,
    const float* __restrict__ hv,
    const float* __restrict__ ws_hq0h, const float* __restrict__ ws_g0h,
    const float* __restrict__ ws_Qh, const float* __restrict__ ws_rhigh,
    const float* __restrict__ ws_M1h, const unsigned* __restrict__ ws_hkeys,
    int* __restrict__ ws_hidx, float* __restrict__ ws_hlogp) {
  int b = blockIdx.x, tid = threadIdx.x;
  int lane = tid & 63, w = tid >> 6;
  __shared__ float s[H_], addM[H_], hq0[H_], g0[H_], hvv[H_];
  __shared__ float uarr[NC_];
  __shared__ int prev_s;
  __shared__ unsigned hm_s;
  __shared__ float acc_s;
  hq0[tid] = ws_hq0h[(size_t)b*H_ + tid];
  g0[tid] = ws_g0h[tid];
  hvv[tid] = hv[tid];
  if (tid == 0) {
    unsigned m = 0;
    for (int c = 0; c < NC_; ++c) if (high_mask[b*NC_ + c] > 0) m |= (1u << c);
    hm_s = m; acc_s = 0.f; prev_s = 0;
  }
  __syncthreads();
  for (int t = 0; t < NC_; ++t) {
    {
      float v = hq0[tid];
      if (t == 0) v += g0[tid];
      else        v += addM[tid] + ws_Qh[(size_t)(b*NC_ + prev_s)*H_ + tid];
      s[tid] = v;
    }
    __syncthreads();
    unsigned hm = hm_s;
    for (int q8 = 0; q8 < 8; ++q8) {
      int cidx = w*8 + q8;
      if ((hm >> cidx) & 1u) continue;
      const float* rr = ws_rhigh + (size_t)(b*NC_ + cidx)*H_;
      float a = 0.f;
#pragma unroll
      for (int jj = 0; jj < 4; ++jj) {
        int h = lane + 64*jj;
        a += hvv[h] * ftanh(s[h] + rr[h]);
      }
#pragma unroll
      for (int off = 32; off; off >>= 1) a += __shfl_xor(a, off);
      if (lane == 0) uarr[cidx] = 10.0f * ftanh(a);
    }
    __syncthreads();
    if (w == 0) {
      int cidx = lane;
      bool valid = (cidx < NC_);
      bool masked = valid && ((hm >> cidx) & 1u);
      float logit = valid ? (masked ? -1e9f : uarr[cidx]) : -INFINITY;
      float val = -INFINITY;
      if (valid) {
        float g = gumbel_bits(ws_hkeys[2*t], ws_hkeys[2*t+1],
                              (unsigned)(b*NC_ + cidx));
        val = logit + g;
      }
      float bvv = val; int bi = valid ? cidx : 9999;
#pragma unroll
      for (int off = 32; off; off >>= 1) {
        float ov = __shfl_xor(bvv, off); int oi = __shfl_xor(bi, off);
        if (ov > bvv || (ov == bvv && oi < bi)) { bvv = ov; bi = oi; }
      }
      float m = logit;
#pragma unroll
      for (int off = 32; off; off >>= 1) m = fmaxf(m, __shfl_xor(m, off));
      float ex = (valid && !masked) ? expf(logit - m) : 0.f;
#pragma unroll
      for (int off = 32; off; off >>= 1) ex += __shfl_xor(ex, off);
      float lsel = __shfl(logit, bi);
      float logp = lsel - m - logf(ex);
      if (lane == 0) {
        acc_s += logp;
        ws_hidx[b*NC_ + t] = bi;
        hm_s = hm | (1u << bi);
        prev_s = bi;
      }
    }
    __syncthreads();
    if (t == 0) {
      {
        int idx0 = prev_s;
        const float* crow = cell_ctx + (size_t)(b*NC_ + idx0)*E_;
        float a = 0.f;
        for (int e = 0; e < E_; ++e)
          a = fmaf(crow[e], ws_M1h[(size_t)e*H_ + tid], a);
        addM[tid] = a;
      }
      __syncthreads();
    }
  }
  if (tid == 0) ws_hlogp[b] = acc_s;
}

// ---------------- idx0 sampling (step 0) per (b,t) ----------------
__global__ __launch_bounds__(256) void k_idx0(
    const int* __restrict__ low_mask, const unsigned* __restrict__ lkeys,
    const int* __restrict__ hidx, const float* __restrict__ u0,
    int* __restrict__ arow, int* __restrict__ cellarr) {
  int tid = threadIdx.x, lane = tid & 63, w = tid >> 6;
  int o = blockIdx.x * 4 + w;
  int b = o >> 5, t = o & 31;
  int c = hidx[o], cell = b*NC_ + c;
  float logit = (low_mask[(size_t)cell*64 + lane] > 0) ? -1e9f
               : u0[(size_t)cell*64 + lane];
  unsigned s0, s1;
  tf2x32(lkeys[2*t], lkeys[2*t+1], 0u, 0u, s0, s1);
  float g = gumbel_bits(s0, s1, (unsigned)(b*NL_ + lane));
  float val = logit + g;
  float bvv = val; int bi = lane;
#pragma unroll
  for (int off = 32; off; off >>= 1) {
    float ov = __shfl_xor(bvv, off); int oi = __shfl_xor(bi, off);
    if (ov > bvv || (ov == bvv && oi < bi)) { bvv = ov; bi = oi; }
  }
  if (lane == 0) { arow[o] = cell*64 + bi; cellarr[o] = cell; }
}

// ---------------- U table v2: register-blocked n, pre-doubled args ----------------
#define S_LDS 260
__global__ __launch_bounds__(512, 3) void k_utab(
    const float* __restrict__ R, const float* __restrict__ Qm,
    const float* __restrict__ sbase, const float* __restrict__ lv,
    const int* __restrict__ hidx, float* __restrict__ U) {
  __shared__ float r_lds[32 * S_LDS];   // 32 rows of 2*r
  __shared__ float qrow[8][264];        // per-wave 2*(sbase+Q[j])
  __shared__ float lvs[256];
  int tid = threadIdx.x, lane = tid & 63, w = tid >> 6;
  int o = blockIdx.x;
  int c = hidx[o], cell = (o >> 5) * NC_ + c;
  const float* Rb = R + (size_t)cell * 16384;
  const float* Qb = Qm + (size_t)cell * 16384;
  if (tid < 64) *(float4*)&lvs[4*tid] = *(const float4*)&lv[4*tid];
  float4 sb4 = *(const float4*)&sbase[(size_t)o*256 + 4*lane];
  int g = lane & 7;          // n-group: rows {g, g+8, g+16, g+24} (interleaved)
  int q = lane >> 3;         // h-eighth: floats q*32 .. q*32+31
  float* qw = qrow[w];
  for (int p = 0; p < 2; ++p) {
    if (p) __syncthreads();
    // stage rows p*32..+31, doubled (exact), fully coalesced
#pragma unroll
    for (int k = 0; k < 4; ++k) {
      int f = tid + 512*k;
      int nl = f >> 6, h4 = (f & 63) * 4;
      float4 v = *(const float4*)&Rb[(size_t)(p*32 + nl)*256 + h4];
      *(float4*)&r_lds[nl*S_LDS + h4] =
          make_float4(2.f*v.x, 2.f*v.y, 2.f*v.z, 2.f*v.w);
    }
    __syncthreads();
    for (int jj = 0; jj < 8; ++jj) {
      int j = w*8 + jj;
      {
        float4 q4 = *(const float4*)&Qb[(size_t)j*256 + 4*lane];
        *(float4*)&qw[4*lane] =
            make_float4(2.f*(sb4.x + q4.x), 2.f*(sb4.y + q4.y),
                        2.f*(sb4.z + q4.z), 2.f*(sb4.w + q4.w));
      }
      // in-wave LDS RAW (qw): DS ops from one wave execute in order (proven r3)
      float4 acc[4];
#pragma unroll
      for (int i = 0; i < 4; ++i) acc[i] = make_float4(0.f, 0.f, 0.f, 0.f);
#pragma unroll
      for (int cc = 0; cc < 8; ++cc) {
        int hh = q*32 + 4*cc;
        float4 qv = *(float4*)&qw[hh];
        float4 l4 = *(float4*)&lvs[hh];
#pragma unroll
        for (int i = 0; i < 4; ++i) {
          float4 rv = *(float4*)&r_lds[(g + 8*i)*S_LDS + hh];
          acc[i].x = fmaf(l4.x, ftanh2(qv.x + rv.x), acc[i].x);
          acc[i].y = fmaf(l4.y, ftanh2(qv.y + rv.y), acc[i].y);
          acc[i].z = fmaf(l4.z, ftanh2(qv.z + rv.z), acc[i].z);
          acc[i].w = fmaf(l4.w, ftanh2(qv.w + rv.w), acc[i].w);
        }
      }
      float s[4];
#pragma unroll
      for (int i = 0; i < 4; ++i) {
        float a = (acc[i].x + acc[i].y) + (acc[i].z + acc[i].w);
        a += __shfl_xor(a, 8);
        a += __shfl_xor(a, 16);
        a += __shfl_xor(a, 32);
        s[i] = a;
      }
      if (lane < 8) {
        float* Uo = U + (size_t)o*4096 + j*64 + p*32 + g;
#pragma unroll
        for (int i = 0; i < 4; ++i)
          Uo[8*i] = 10.0f * ftanh(s[i]);
      }
    }
  }
}

// ---------------- sequential low sampler: one wave per (b,t) ----------------
__global__ __launch_bounds__(256) void k_lowseq(
    const float* __restrict__ orig, const int* __restrict__ low_mask,
    const unsigned* __restrict__ lkeys, const int* __restrict__ hidx,
    const float* __restrict__ u0, const float* __restrict__ U,
    float* __restrict__ llogp, float* __restrict__ lRr,
    float* __restrict__ lastn, float* __restrict__ initn) {
  int tid = threadIdx.x, lane = tid & 63, w = tid >> 6;
  int o = blockIdx.x * 4 + w;
  int b = o >> 5, t = o & 31;
  int c = hidx[o], cell = b*NC_ + c;
  float cx = orig[(size_t)cell*128 + 2*lane];
  float cy = orig[(size_t)cell*128 + 2*lane + 1];
  int maskb = (low_mask[(size_t)cell*64 + lane] > 0) ? 1 : 0;
  unsigned sk0, sk1;
  tf2x32(lkeys[2*t], lkeys[2*t+1], 0u, (unsigned)lane, sk0, sk1);
  float row = u0[(size_t)cell*64 + lane];
  float px = __shfl(cx, 0), py = __shfl(cy, 0);
  float ix = px, iy = py;
  float lp = 0.f, rw = 0.f;
  const float* Ub = U + (size_t)o * 4096;
  for (int s = 0; s < NL_; ++s) {
    float logit = maskb ? -1e9f : row;
    unsigned k0 = (unsigned)__shfl((int)sk0, s);
    unsigned k1 = (unsigned)__shfl((int)sk1, s);
    float g = gumbel_bits(k0, k1, (unsigned)(b*NL_ + lane));
    float val = logit + g;
    float bvv = val; int bi = lane;
#pragma unroll
    for (int off = 32; off; off >>= 1) {
      float ov = __shfl_xor(bvv, off); int oi = __shfl_xor(bi, off);
      if (ov > bvv || (ov == bvv && oi < bi)) { bvv = ov; bi = oi; }
    }
    float nrow = Ub[(size_t)bi*64 + lane];
    float m = logit;
#pragma unroll
    for (int off = 32; off; off >>= 1) m = fmaxf(m, __shfl_xor(m, off));
    float ex = maskb ? 0.f : expf(logit - m);
#pragma unroll
    for (int off = 32; off; off >>= 1) ex += __shfl_xor(ex, off);
    float lsel = __shfl(logit, bi);
    lp += lsel - m - logf(ex);
    float bx = __shfl(cx, bi), by = __shfl(cy, bi);
    float dx = bx - px, dy = by - py;
    rw += sqrtf(dx*dx + dy*dy + 1e-12f);
    px = bx; py = by;
    if (lane == bi) maskb = 1;
    row = nrow;
  }
  if (lane == 0) {
    llogp[o] = lp; lRr[o] = rw;
    lastn[2*o] = px; lastn[2*o+1] = py;
    initn[2*o] = ix; initn[2*o+1] = iy;
  }
}

// ---------------- phase C: stitch ----------------
__global__ __launch_bounds__(64) void k_stitch(
    const float* __restrict__ ws_hlogp, const float* __restrict__ ws_llogp,
    const float* __restrict__ ws_lR, const float* __restrict__ ws_lastn,
    const float* __restrict__ ws_initn, float* __restrict__ out) {
  int b = threadIdx.x;
  if (b >= B_) return;
  float lp = ws_hlogp[b], rw = 0.f, lx = 0.f, ly = 0.f;
  for (int t = 0; t < NC_; ++t) {
    int o = b*NC_ + t;
    lp += ws_llogp[o];
    float dx = ws_initn[2*o] - lx, dy = ws_initn[2*o+1] - ly;
    rw += ws_lR[o] + sqrtf(dx*dx + dy*dy + 1e-12f);
    lx = ws_lastn[2*o]; ly = ws_lastn[2*o+1];
  }
  out[b] = lp;
  out[B_ + b] = rw;
}

// ---------------- host launcher ----------------
extern "C" void kernel_launch(void* const* d_in, const int* in_sizes, int n_in,
                              void* d_out, int out_size, void* d_ws, size_t ws_size,
                              hipStream_t stream) {
  const float* node_ctx  = (const float*)d_in[0];
  const float* cell_ctx  = (const float*)d_in[1];
  const float* orig      = (const float*)d_in[2];
  const int*   high_mask = (const int*)d_in[3];
  const int*   low_mask  = (const int*)d_in[4];
  const float* init_w    = (const float*)d_in[5];
  const float* Wc        = (const float*)d_in[6];
  const float* bc        = (const float*)d_in[7];
  const float* Wv        = (const float*)d_in[8];
  const float* bv        = (const float*)d_in[9];
  const float* hWq       = (const float*)d_in[10];
  const float* hbq       = (const float*)d_in[11];
  const float* hWr       = (const float*)d_in[12];
  const float* hbr       = (const float*)d_in[13];
  const float* hv        = (const float*)d_in[14];
  const float* low_init_w= (const float*)d_in[15];
  const float* lWc       = (const float*)d_in[16];
  const float* lbc       = (const float*)d_in[17];
  const float* lWv       = (const float*)d_in[18];
  const float* lbv       = (const float*)d_in[19];
  const float* lWq       = (const float*)d_in[20];
  const float* lbq       = (const float*)d_in[21];
  const float* lWr       = (const float*)d_in[22];
  const float* lbr       = (const float*)d_in[23];
  const float* lv        = (const float*)d_in[24];
  float* out = (float*)d_out;

  char* ws = (char*)d_ws;
  size_t off = 0;
  auto alloc = [&](size_t bytes) -> void* {
    void* p = ws + off;
    off += (bytes + 255) & ~(size_t)255;
    return p;
  };
  unsigned* w_hkeys = (unsigned*)alloc(32*2*4);
  unsigned* w_lkeys = (unsigned*)alloc(32*2*4);
  int*   w_hidx  = (int*)alloc(2048*4);
  int*   w_arow  = (int*)alloc(2048*4);
  int*   w_cell  = (int*)alloc(2048*4);
  float* w_hlogp = (float*)alloc(64*4);
  float* w_llogp = (float*)alloc(2048*4);
  float* w_lR    = (float*)alloc(2048*4);
  float* w_lastn = (float*)alloc(2048*2*4);
  float* w_initn = (float*)alloc(2048*2*4);
  float* w_g0h   = (float*)alloc(256*4);
  float* w_g0l   = (float*)alloc(256*4);
  float* w_M1h   = (float*)alloc((size_t)65536*4);
  float* w_Ah    = (float*)alloc((size_t)65536*4);
  float* w_M1l   = (float*)alloc((size_t)65536*4);
  float* w_Al    = (float*)alloc((size_t)65536*4);
  float* w_mcc   = (float*)alloc((size_t)64*256*4);
  float* w_mnc   = (float*)alloc((size_t)2048*256*4);
  float* w_hbh   = (float*)alloc((size_t)64*256*4);
  float* w_hq0h  = (float*)alloc((size_t)64*256*4);
  float* w_rhigh = (float*)alloc((size_t)2048*256*4);
  float* w_Qh    = (float*)alloc((size_t)2048*256*4);
  float* w_hbl   = (float*)alloc((size_t)2048*256*4);
  float* w_hq0l  = (float*)alloc((size_t)2048*256*4);
  float* w_u0    = (float*)alloc((size_t)2048*64*4);
  float* w_sbase = (float*)alloc((size_t)2048*256*4);
  float* w_U     = (float*)alloc((size_t)2048*4096*4);
  float* w_R     = (float*)alloc((size_t)2048*64*256*4);
  float* w_Qm    = (float*)alloc((size_t)2048*64*256*4);
  (void)ws_size; (void)in_sizes; (void)n_in; (void)out_size;

  k0_kernel<<<1, 256, 0, stream>>>(init_w, Wv, hWq, low_init_w, lWv, lWq,
                                   w_hkeys, w_lkeys, w_g0h, w_g0l);
  k_mean<<<2048, 256, 0, stream>>>(node_ctx, w_mnc, 64);
  k_mean<<<64, 256, 0, stream>>>(cell_ctx, w_mcc, 32);

  dim3 g256(16, 4), g2048(128, 4), g64(4, 4);
  k_gemm<<<g256, 256, 0, stream>>>(Wv,            256, nullptr, hWq, nullptr, w_M1h, 256, 256, 256);
  k_gemm<<<g256, 256, 0, stream>>>(Wv + 65536,    256, nullptr, hWq, nullptr, w_Ah,  256, 256, 256);
  k_gemm<<<g256, 256, 0, stream>>>(lWv,           256, nullptr, lWq, nullptr, w_M1l, 256, 256, 256);
  k_gemm<<<g256, 256, 0, stream>>>(lWv + 65536,   256, nullptr, lWq, nullptr, w_Al,  256, 256, 256);
  k_gemm<<<g2048, 256, 0, stream>>>(cell_ctx, 256, nullptr, hWr, hbr, w_rhigh, 2048, 256, 256);
  k_gemm<<<g2048, 256, 0, stream>>>(cell_ctx, 256, nullptr, w_Ah, nullptr, w_Qh, 2048, 256, 256);
  k_gemm<<<g64,   256, 0, stream>>>(w_mcc, 256, nullptr, Wc,  bc,  w_hbh, 64,   256, 256);
  k_gemm<<<g2048, 256, 0, stream>>>(w_mnc, 256, nullptr, lWc, lbc, w_hbl, 2048, 256, 256);
  k_gemm<<<g64,   256, 0, stream>>>(w_hbh, 256, bv,  hWq, hbq, w_hq0h, 64,   256, 256);
  k_gemm<<<g2048, 256, 0, stream>>>(w_hbl, 256, lbv, lWq, lbq, w_hq0l, 2048, 256, 256);

  k_bgemm<<<dim3(1024, 4), 256, 0, stream>>>(node_ctx, lWr, w_Al, lbr, w_R, w_Qm);
  k_u0k<<<2048, 256, 0, stream>>>(w_R, w_hq0l, w_g0l, lv, w_u0);

  k_high<<<64, 256, 0, stream>>>(cell_ctx, high_mask, hv, w_hq0h, w_g0h, w_Qh,
                                 w_rhigh, w_M1h, w_hkeys, w_hidx, w_hlogp);
  k_idx0<<<512, 256, 0, stream>>>(low_mask, w_lkeys, w_hidx, w_u0, w_arow, w_cell);
  k_gemmg<<<dim3(128, 4), 256, 0, stream>>>(node_ctx, w_arow, w_cell, w_M1l,
                                            w_hq0l, w_sbase);
  k_utab<<<2048, 512, 0, stream>>>(w_R, w_Qm, w_sbase, lv, w_hidx, w_U);
  k_lowseq<<<512, 256, 0, stream>>>(orig, low_mask, w_lkeys, w_hidx, w_u0, w_U,
                                    w_llogp, w_lR, w_lastn, w_initn);
  k_stitch<<<1, 64, 0, stream>>>(w_hlogp, w_llogp, w_lR, w_lastn, w_initn, out);
}

// Round 5
// 1577.652 us; speedup vs baseline: 2.0777x; 1.2296x over previous
//
#include <hip/hip_runtime.h>
#include <cstdint>
#include <cstddef>

#define B_  64
#define NC_ 32
#define NL_ 64
#define E_  256
#define H_  256

// ---------------- Threefry-2x32, 20 rounds (JAX-compatible) ----------------
__device__ __forceinline__ void tf2x32(unsigned k0, unsigned k1,
                                       unsigned c0, unsigned c1,
                                       unsigned &o0, unsigned &o1) {
  unsigned ks2 = k0 ^ k1 ^ 0x1BD11BDAu;
  unsigned x0 = c0 + k0, x1 = c1 + k1;
#define TFR(r) { x0 += x1; x1 = (x1 << r) | (x1 >> (32 - r)); x1 ^= x0; }
  TFR(13) TFR(15) TFR(26) TFR(6)   x0 += k1;  x1 += ks2 + 1u;
  TFR(17) TFR(29) TFR(16) TFR(24)  x0 += ks2; x1 += k0 + 2u;
  TFR(13) TFR(15) TFR(26) TFR(6)   x0 += k0;  x1 += k1 + 3u;
  TFR(17) TFR(29) TFR(16) TFR(24)  x0 += k1;  x1 += ks2 + 4u;
  TFR(13) TFR(15) TFR(26) TFR(6)   x0 += ks2; x1 += k0 + 5u;
#undef TFR
  o0 = x0; o1 = x1;
}

__device__ __forceinline__ float gumbel_bits(unsigned k0, unsigned k1, unsigned flat) {
  unsigned a, b;
  tf2x32(k0, k1, 0u, flat, a, b);
  unsigned bits = a ^ b;
  float f = __uint_as_float(0x3F800000u | (bits >> 9)) - 1.0f;
  f = fmaxf(f, 1.17549435e-38f);
  return -logf(-logf(f));
}

// tanh via native exp + native rcp (no IEEE divide sequence).
__device__ __forceinline__ float ftanh(float x) {
  float e = __expf(2.0f * x);
  return fmaf(-2.0f, __builtin_amdgcn_rcpf(e + 1.0f), 1.0f);
}

// ---------------- K0: keys + init vectors + sum(lv) ----------------
__global__ __launch_bounds__(256) void k0_kernel(
    const float* __restrict__ init_w, const float* __restrict__ Wv,
    const float* __restrict__ hWq,
    const float* __restrict__ low_init_w, const float* __restrict__ lWv,
    const float* __restrict__ lWq, const float* __restrict__ lvin,
    unsigned* __restrict__ hkeys, unsigned* __restrict__ lkeys,
    float* __restrict__ g0h, float* __restrict__ g0l,
    float* __restrict__ Lsum) {
  int tid = threadIdx.x;
  __shared__ float s_iwv[E_], s_liwv[E_];
  if (tid < 32) {
    unsigned a, b;
    tf2x32(0u, 42u, 0u, (unsigned)tid, a, b);
    hkeys[2*tid] = a; hkeys[2*tid+1] = b;
    tf2x32(0u, 7u, 0u, (unsigned)tid, a, b);
    lkeys[2*tid] = a; lkeys[2*tid+1] = b;
  }
  if (tid == 0) {
    float s = 0.f;
    for (int k = 0; k < 256; ++k) s += lvin[k];
    Lsum[0] = s;
  }
  {
    float a = 0.f, a2 = 0.f;
    for (int k = 0; k < 2*E_; ++k) {
      a  = fmaf(init_w[k],     Wv[(size_t)k*E_ + tid], a);
      a2 = fmaf(low_init_w[k], lWv[(size_t)k*E_ + tid], a2);
    }
    s_iwv[tid] = a; s_liwv[tid] = a2;
  }
  __syncthreads();
  {
    float a = 0.f, a2 = 0.f;
    for (int e = 0; e < E_; ++e) {
      a  = fmaf(s_iwv[e],  hWq[(size_t)e*H_ + tid], a);
      a2 = fmaf(s_liwv[e], lWq[(size_t)e*H_ + tid], a2);
    }
    g0h[tid] = a; g0l[tid] = a2;
  }
}

// ---------------- means over middle dim ----------------
__global__ __launch_bounds__(256) void k_mean(const float* __restrict__ in,
                                              float* __restrict__ out, int G) {
  int row = blockIdx.x, h = threadIdx.x;
  const float* p = in + (size_t)row * G * E_ + h;
  float a = 0.f;
  for (int g = 0; g < G; ++g) a += p[(size_t)g * E_];
  out[(size_t)row * E_ + h] = a * (1.0f / G);
}

// ---------------- generic small GEMM: C = (A .+ avec) @ W + bias ----------------
__global__ __launch_bounds__(256) void k_gemm(
    const float* __restrict__ A, int lda, const float* __restrict__ avec,
    const float* __restrict__ W, const float* __restrict__ bias,
    float* __restrict__ C, int M, int N, int K) {
  __shared__ float As[16][17];
  int i0 = blockIdx.x * 16, j0 = blockIdx.y * 64;
  int tx = threadIdx.x & 63, ty = threadIdx.x >> 6;
  int j = j0 + tx;
  float acc[4] = {0.f, 0.f, 0.f, 0.f};
  for (int kk = 0; kk < K; kk += 16) {
    int r = threadIdx.x >> 4, cc = threadIdx.x & 15;
    float av = A[(size_t)(i0 + r) * lda + kk + cc];
    if (avec) av += avec[kk + cc];
    As[r][cc] = av;
    __syncthreads();
#pragma unroll
    for (int kt = 0; kt < 16; ++kt) {
      float w = W[(size_t)(kk + kt) * N + j];
#pragma unroll
      for (int k2 = 0; k2 < 4; ++k2)
        acc[k2] = fmaf(As[ty*4 + k2][kt], w, acc[k2]);
    }
    __syncthreads();
  }
  float bb = bias ? bias[j] : 0.f;
#pragma unroll
  for (int k2 = 0; k2 < 4; ++k2)
    C[(size_t)(i0 + ty*4 + k2) * N + j] = acc[k2] + bb;
}

// ---------------- gathered GEMM: sbase[o] = hq0l[cell_o] + node_ctx[arow_o] @ M1l ----------------
__global__ __launch_bounds__(256) void k_gemmg(
    const float* __restrict__ nodectx, const int* __restrict__ arow,
    const int* __restrict__ cellarr, const float* __restrict__ W,
    const float* __restrict__ hq0l, float* __restrict__ C) {
  __shared__ float As[16][17];
  __shared__ int rows[16];
  int i0 = blockIdx.x * 16, j0 = blockIdx.y * 64;
  int tx = threadIdx.x & 63, ty = threadIdx.x >> 6;
  int j = j0 + tx;
  if (threadIdx.x < 16) rows[threadIdx.x] = arow[i0 + threadIdx.x];
  __syncthreads();
  float acc[4] = {0.f, 0.f, 0.f, 0.f};
  for (int kk = 0; kk < 256; kk += 16) {
    int r = threadIdx.x >> 4, cc = threadIdx.x & 15;
    As[r][cc] = nodectx[(size_t)rows[r] * 256 + kk + cc];
    __syncthreads();
#pragma unroll
    for (int kt = 0; kt < 16; ++kt) {
      float w = W[(size_t)(kk + kt) * 256 + j];
#pragma unroll
      for (int k2 = 0; k2 < 4; ++k2)
        acc[k2] = fmaf(As[ty*4 + k2][kt], w, acc[k2]);
    }
    __syncthreads();
  }
#pragma unroll
  for (int k2 = 0; k2 < 4; ++k2) {
    int row = i0 + ty*4 + k2;
    C[(size_t)row * 256 + j] = acc[k2] + hq0l[(size_t)cellarr[row] * 256 + j];
  }
}

// ---------------- big GEMM: [R|Q] = node_ctx(131072x256) @ [lWr | Al](256x512) ----------------
__global__ __launch_bounds__(256, 2) void k_bgemm(
    const float* __restrict__ A, const float* __restrict__ Wr,
    const float* __restrict__ Alm, const float* __restrict__ lbr,
    float* __restrict__ Rout, float* __restrict__ Qout) {
  __shared__ float As[16][132];
  __shared__ float Ws[16][132];
  int bx = blockIdx.x, by = blockIdx.y;
  const float* Wbase = (by < 2) ? Wr : Alm;
  float* Cbase = (by < 2) ? Rout : Qout;
  int jb = (by & 1) * 128;
  bool doBias = (by < 2);
  int m0 = bx * 128;
  int tid = threadIdx.x;
  int tx = tid & 15, ty = tid >> 4;
  float acc[8][8];
#pragma unroll
  for (int i = 0; i < 8; ++i)
#pragma unroll
    for (int j = 0; j < 8; ++j) acc[i][j] = 0.f;

  for (int kc = 0; kc < 256; kc += 16) {
    {
      int kq = (tid & 3) * 4;
#pragma unroll
      for (int p = 0; p < 2; ++p) {
        int m = (tid >> 2) + p * 64;
        float4 a4 = *(const float4*)&A[(size_t)(m0 + m) * 256 + kc + kq];
        As[kq + 0][m] = a4.x; As[kq + 1][m] = a4.y;
        As[kq + 2][m] = a4.z; As[kq + 3][m] = a4.w;
      }
      int k = tid >> 4;
      int c4 = (tid & 15) * 8;
      float4 w0 = *(const float4*)&Wbase[(size_t)(kc + k) * 256 + jb + c4];
      float4 w1 = *(const float4*)&Wbase[(size_t)(kc + k) * 256 + jb + c4 + 4];
      *(float4*)&Ws[k][c4] = w0;
      *(float4*)&Ws[k][c4 + 4] = w1;
    }
    __syncthreads();
#pragma unroll
    for (int k = 0; k < 16; ++k) {
      float4 a0 = *(float4*)&As[k][ty * 8];
      float4 a1 = *(float4*)&As[k][ty * 8 + 4];
      float4 w0 = *(float4*)&Ws[k][tx * 8];
      float4 w1 = *(float4*)&Ws[k][tx * 8 + 4];
      float av[8] = {a0.x, a0.y, a0.z, a0.w, a1.x, a1.y, a1.z, a1.w};
      float wv[8] = {w0.x, w0.y, w0.z, w0.w, w1.x, w1.y, w1.z, w1.w};
#pragma unroll
      for (int i = 0; i < 8; ++i)
#pragma unroll
        for (int j = 0; j < 8; ++j)
          acc[i][j] = fmaf(av[i], wv[j], acc[i][j]);
    }
    __syncthreads();
  }
  float bias[8];
#pragma unroll
  for (int j = 0; j < 8; ++j)
    bias[j] = doBias ? lbr[jb + tx * 8 + j] : 0.f;
#pragma unroll
  for (int i = 0; i < 8; ++i) {
    float4 o0 = make_float4(acc[i][0] + bias[0], acc[i][1] + bias[1],
                            acc[i][2] + bias[2], acc[i][3] + bias[3]);
    float4 o1 = make_float4(acc[i][4] + bias[4], acc[i][5] + bias[5],
                            acc[i][6] + bias[6], acc[i][7] + bias[7]);
    size_t base = (size_t)(m0 + ty * 8 + i) * 256 + jb + tx * 8;
    *(float4*)&Cbase[base] = o0;
    *(float4*)&Cbase[base + 4] = o1;
  }
}

// ---------------- u0 for all cells ----------------
__global__ __launch_bounds__(256) void k_u0k(
    const float* __restrict__ R, const float* __restrict__ hq0l,
    const float* __restrict__ g0l, const float* __restrict__ lv,
    float* __restrict__ u0) {
  int cell = blockIdx.x, tid = threadIdx.x, lane = tid & 63, w = tid >> 6;
  __shared__ float qs[256];
  qs[tid] = hq0l[(size_t)cell*256 + tid] + g0l[tid];
  __syncthreads();
  float lvr[4], qsr[4];
#pragma unroll
  for (int q = 0; q < 4; ++q) { lvr[q] = lv[lane + 64*q]; qsr[q] = qs[lane + 64*q]; }
  const float* Rb = R + (size_t)cell * 16384;
  for (int i = 0; i < 16; ++i) {
    int n = w*16 + i;
    const float* rr = Rb + (size_t)n*256;
    float a = 0.f;
#pragma unroll
    for (int q = 0; q < 4; ++q)
      a = fmaf(lvr[q], ftanh(qsr[q] + rr[lane + 64*q]), a);
#pragma unroll
    for (int off = 32; off; off >>= 1) a += __shfl_xor(a, off);
    if (lane == 0) u0[(size_t)cell*64 + n] = 10.0f * ftanh(a);
  }
}

// ---------------- phase A: high-level sampling chain ----------------
__global__ __launch_bounds__(256) void k_high(
    const float* __restrict__ cell_ctx, const int* __restrict__ high_mask,
    const float* __restrict__ hv,
    const float* __restrict__ ws_hq0h, const float* __restrict__ ws_g0h,
    const float* __restrict__ ws_Qh, const float* __restrict__ ws_rhigh,
    const float* __restrict__ ws_M1h, const unsigned* __restrict__ ws_hkeys,
    int* __restrict__ ws_hidx, float* __restrict__ ws_hlogp) {
  int b = blockIdx.x, tid = threadIdx.x;
  int lane = tid & 63, w = tid >> 6;
  __shared__ float s[H_], addM[H_], hq0[H_], g0[H_], hvv[H_];
  __shared__ float uarr[NC_];
  __shared__ int prev_s;
  __shared__ unsigned hm_s;
  __shared__ float acc_s;
  hq0[tid] = ws_hq0h[(size_t)b*H_ + tid];
  g0[tid] = ws_g0h[tid];
  hvv[tid] = hv[tid];
  if (tid == 0) {
    unsigned m = 0;
    for (int c = 0; c < NC_; ++c) if (high_mask[b*NC_ + c] > 0) m |= (1u << c);
    hm_s = m; acc_s = 0.f; prev_s = 0;
  }
  __syncthreads();
  for (int t = 0; t < NC_; ++t) {
    {
      float v = hq0[tid];
      if (t == 0) v += g0[tid];
      else        v += addM[tid] + ws_Qh[(size_t)(b*NC_ + prev_s)*H_ + tid];
      s[tid] = v;
    }
    __syncthreads();
    unsigned hm = hm_s;
    for (int q8 = 0; q8 < 8; ++q8) {
      int cidx = w*8 + q8;
      if ((hm >> cidx) & 1u) continue;
      const float* rr = ws_rhigh + (size_t)(b*NC_ + cidx)*H_;
      float a = 0.f;
#pragma unroll
      for (int jj = 0; jj < 4; ++jj) {
        int h = lane + 64*jj;
        a += hvv[h] * ftanh(s[h] + rr[h]);
      }
#pragma unroll
      for (int off = 32; off; off >>= 1) a += __shfl_xor(a, off);
      if (lane == 0) uarr[cidx] = 10.0f * ftanh(a);
    }
    __syncthreads();
    if (w == 0) {
      int cidx = lane;
      bool valid = (cidx < NC_);
      bool masked = valid && ((hm >> cidx) & 1u);
      float logit = valid ? (masked ? -1e9f : uarr[cidx]) : -INFINITY;
      float val = -INFINITY;
      if (valid) {
        float g = gumbel_bits(ws_hkeys[2*t], ws_hkeys[2*t+1],
                              (unsigned)(b*NC_ + cidx));
        val = logit + g;
      }
      float bvv = val; int bi = valid ? cidx : 9999;
#pragma unroll
      for (int off = 32; off; off >>= 1) {
        float ov = __shfl_xor(bvv, off); int oi = __shfl_xor(bi, off);
        if (ov > bvv || (ov == bvv && oi < bi)) { bvv = ov; bi = oi; }
      }
      float m = logit;
#pragma unroll
      for (int off = 32; off; off >>= 1) m = fmaxf(m, __shfl_xor(m, off));
      float ex = (valid && !masked) ? expf(logit - m) : 0.f;
#pragma unroll
      for (int off = 32; off; off >>= 1) ex += __shfl_xor(ex, off);
      float lsel = __shfl(logit, bi);
      float logp = lsel - m - logf(ex);
      if (lane == 0) {
        acc_s += logp;
        ws_hidx[b*NC_ + t] = bi;
        hm_s = hm | (1u << bi);
        prev_s = bi;
      }
    }
    __syncthreads();
    if (t == 0) {
      {
        int idx0 = prev_s;
        const float* crow = cell_ctx + (size_t)(b*NC_ + idx0)*E_;
        float a = 0.f;
        for (int e = 0; e < E_; ++e)
          a = fmaf(crow[e], ws_M1h[(size_t)e*H_ + tid], a);
        addM[tid] = a;
      }
      __syncthreads();
    }
  }
  if (tid == 0) ws_hlogp[b] = acc_s;
}

// ---------------- idx0 sampling (step 0) per (b,t) ----------------
__global__ __launch_bounds__(256) void k_idx0(
    const int* __restrict__ low_mask, const unsigned* __restrict__ lkeys,
    const int* __restrict__ hidx, const float* __restrict__ u0,
    int* __restrict__ arow, int* __restrict__ cellarr) {
  int tid = threadIdx.x, lane = tid & 63, w = tid >> 6;
  int o = blockIdx.x * 4 + w;
  int b = o >> 5, t = o & 31;
  int c = hidx[o], cell = b*NC_ + c;
  float logit = (low_mask[(size_t)cell*64 + lane] > 0) ? -1e9f
               : u0[(size_t)cell*64 + lane];
  unsigned s0, s1;
  tf2x32(lkeys[2*t], lkeys[2*t+1], 0u, 0u, s0, s1);
  float g = gumbel_bits(s0, s1, (unsigned)(b*NL_ + lane));
  float val = logit + g;
  float bvv = val; int bi = lane;
#pragma unroll
  for (int off = 32; off; off >>= 1) {
    float ov = __shfl_xor(bvv, off); int oi = __shfl_xor(bi, off);
    if (ov > bvv || (ov == bvv && oi < bi)) { bvv = ov; bi = oi; }
  }
  if (lane == 0) { arow[o] = cell*64 + bi; cellarr[o] = cell; }
}

// ---------------- U table v3: r3 conflict-free layout, j-pair blocked, lean tanh ----------------
#define S_LDS 260
#define QPAD  264
__global__ __launch_bounds__(512, 6) void k_utab(
    const float* __restrict__ R, const float* __restrict__ Qm,
    const float* __restrict__ sbase, const float* __restrict__ lv,
    const float* __restrict__ Lsum, const int* __restrict__ hidx,
    float* __restrict__ U) {
  __shared__ float r_lds[32 * S_LDS];     // 32 rows of 2*r  (33.3 KB)
  __shared__ float qrow[8][2 * QPAD];     // per-wave 2*(sbase+Q[j0]),[j0+1] (16.9 KB)
  __shared__ float lvs[256];
  int tid = threadIdx.x, lane = tid & 63, w = tid >> 6;
  int o = blockIdx.x;
  int c = hidx[o], cell = (o >> 5) * NC_ + c;
  const float* Rb = R + (size_t)cell * 16384;
  const float* Qb = Qm + (size_t)cell * 16384;
  if (tid < 64) *(float4*)&lvs[4*tid] = *(const float4*)&lv[4*tid];
  float Ls = Lsum[0];
  float4 sb4 = *(const float4*)&sbase[(size_t)o*256 + 4*lane];
  int rbase = (lane >> 5) * 128;   // h-half this lane covers
  int nloc = lane & 31;            // local row index (conflict-free: measured r3)
  float* qw = qrow[w];
  for (int p = 0; p < 2; ++p) {
    if (p) __syncthreads();
    // stage rows p*32..+31, doubled (exact), fully coalesced
#pragma unroll
    for (int k = 0; k < 4; ++k) {
      int f = tid + 512*k;
      int nl = f >> 6, h4 = (f & 63) * 4;
      float4 v = *(const float4*)&Rb[(size_t)(p*32 + nl)*256 + h4];
      *(float4*)&r_lds[nl*S_LDS + h4] =
          make_float4(v.x + v.x, v.y + v.y, v.z + v.z, v.w + v.w);
    }
    __syncthreads();
    for (int jj = 0; jj < 4; ++jj) {
      int j0 = w*8 + 2*jj;
      {
        float4 qa = *(const float4*)&Qb[(size_t)j0*256 + 4*lane];
        float4 qb = *(const float4*)&Qb[(size_t)(j0+1)*256 + 4*lane];
        *(float4*)&qw[4*lane] =
            make_float4(2.f*(sb4.x + qa.x), 2.f*(sb4.y + qa.y),
                        2.f*(sb4.z + qa.z), 2.f*(sb4.w + qa.w));
        *(float4*)&qw[QPAD + 4*lane] =
            make_float4(2.f*(sb4.x + qb.x), 2.f*(sb4.y + qb.y),
                        2.f*(sb4.z + qb.z), 2.f*(sb4.w + qb.w));
      }
      // in-wave LDS RAW on qw: per-wave DS ordering (r3-proven pattern)
      float4 acc0 = make_float4(0.f, 0.f, 0.f, 0.f);
      float4 acc1 = make_float4(0.f, 0.f, 0.f, 0.f);
#pragma unroll 8
      for (int cc = 0; cc < 32; ++cc) {
        int hh = rbase + 4*cc;
        float4 rv = *(float4*)&r_lds[nloc*S_LDS + hh];
        float4 l4 = *(float4*)&lvs[hh];
        float4 q0 = *(float4*)&qw[hh];
        float4 q1 = *(float4*)&qw[QPAD + hh];
        acc0.x = fmaf(l4.x, __builtin_amdgcn_rcpf(__expf(q0.x + rv.x) + 1.f), acc0.x);
        acc0.y = fmaf(l4.y, __builtin_amdgcn_rcpf(__expf(q0.y + rv.y) + 1.f), acc0.y);
        acc0.z = fmaf(l4.z, __builtin_amdgcn_rcpf(__expf(q0.z + rv.z) + 1.f), acc0.z);
        acc0.w = fmaf(l4.w, __builtin_amdgcn_rcpf(__expf(q0.w + rv.w) + 1.f), acc0.w);
        acc1.x = fmaf(l4.x, __builtin_amdgcn_rcpf(__expf(q1.x + rv.x) + 1.f), acc1.x);
        acc1.y = fmaf(l4.y, __builtin_amdgcn_rcpf(__expf(q1.y + rv.y) + 1.f), acc1.y);
        acc1.z = fmaf(l4.z, __builtin_amdgcn_rcpf(__expf(q1.z + rv.z) + 1.f), acc1.z);
        acc1.w = fmaf(l4.w, __builtin_amdgcn_rcpf(__expf(q1.w + rv.w) + 1.f), acc1.w);
      }
      // u = 10*tanh(L - 2*S) where S = sum lv*rcp
      float a0 = (acc0.x + acc0.y) + (acc0.z + acc0.w);
      float a1 = (acc1.x + acc1.y) + (acc1.z + acc1.w);
      a0 += __shfl_xor(a0, 32);
      a1 += __shfl_xor(a1, 32);
      if (lane < 32) {
        float* Uo = U + (size_t)o*4096 + j0*64 + p*32 + lane;
        Uo[0]  = 10.0f * ftanh(fmaf(-2.f, a0, Ls));
        Uo[64] = 10.0f * ftanh(fmaf(-2.f, a1, Ls));
      }
    }
  }
}

// ---------------- sequential low sampler: one wave per (b,t) ----------------
__global__ __launch_bounds__(256) void k_lowseq(
    const float* __restrict__ orig, const int* __restrict__ low_mask,
    const unsigned* __restrict__ lkeys, const int* __restrict__ hidx,
    const float* __restrict__ u0, const float* __restrict__ U,
    float* __restrict__ llogp, float* __restrict__ lRr,
    float* __restrict__ lastn, float* __restrict__ initn) {
  int tid = threadIdx.x, lane = tid & 63, w = tid >> 6;
  int o = blockIdx.x * 4 + w;
  int b = o >> 5, t = o & 31;
  int c = hidx[o], cell = b*NC_ + c;
  float cx = orig[(size_t)cell*128 + 2*lane];
  float cy = orig[(size_t)cell*128 + 2*lane + 1];
  int maskb = (low_mask[(size_t)cell*64 + lane] > 0) ? 1 : 0;
  unsigned sk0, sk1;
  tf2x32(lkeys[2*t], lkeys[2*t+1], 0u, (unsigned)lane, sk0, sk1);
  float row = u0[(size_t)cell*64 + lane];
  float px = __shfl(cx, 0), py = __shfl(cy, 0);
  float ix = px, iy = py;
  float lp = 0.f, rw = 0.f;
  const float* Ub = U + (size_t)o * 4096;
  for (int s = 0; s < NL_; ++s) {
    float logit = maskb ? -1e9f : row;
    unsigned k0 = (unsigned)__shfl((int)sk0, s);
    unsigned k1 = (unsigned)__shfl((int)sk1, s);
    float g = gumbel_bits(k0, k1, (unsigned)(b*NL_ + lane));
    float val = logit + g;
    float bvv = val; int bi = lane;
#pragma unroll
    for (int off = 32; off; off >>= 1) {
      float ov = __shfl_xor(bvv, off); int oi = __shfl_xor(bi, off);
      if (ov > bvv || (ov == bvv && oi < bi)) { bvv = ov; bi = oi; }
    }
    float nrow = Ub[(size_t)bi*64 + lane];
    float m = logit;
#pragma unroll
    for (int off = 32; off; off >>= 1) m = fmaxf(m, __shfl_xor(m, off));
    float ex = maskb ? 0.f : expf(logit - m);
#pragma unroll
    for (int off = 32; off; off >>= 1) ex += __shfl_xor(ex, off);
    float lsel = __shfl(logit, bi);
    lp += lsel - m - logf(ex);
    float bx = __shfl(cx, bi), by = __shfl(cy, bi);
    float dx = bx - px, dy = by - py;
    rw += sqrtf(dx*dx + dy*dy + 1e-12f);
    px = bx; py = by;
    if (lane == bi) maskb = 1;
    row = nrow;
  }
  if (lane == 0) {
    llogp[o] = lp; lRr[o] = rw;
    lastn[2*o] = px; lastn[2*o+1] = py;
    initn[2*o] = ix; initn[2*o+1] = iy;
  }
}

// ---------------- phase C: stitch ----------------
__global__ __launch_bounds__(64) void k_stitch(
    const float* __restrict__ ws_hlogp, const float* __restrict__ ws_llogp,
    const float* __restrict__ ws_lR, const float* __restrict__ ws_lastn,
    const float* __restrict__ ws_initn, float* __restrict__ out) {
  int b = threadIdx.x;
  if (b >= B_) return;
  float lp = ws_hlogp[b], rw = 0.f, lx = 0.f, ly = 0.f;
  for (int t = 0; t < NC_; ++t) {
    int o = b*NC_ + t;
    lp += ws_llogp[o];
    float dx = ws_initn[2*o] - lx, dy = ws_initn[2*o+1] - ly;
    rw += ws_lR[o] + sqrtf(dx*dx + dy*dy + 1e-12f);
    lx = ws_lastn[2*o]; ly = ws_lastn[2*o+1];
  }
  out[b] = lp;
  out[B_ + b] = rw;
}

// ---------------- host launcher ----------------
extern "C" void kernel_launch(void* const* d_in, const int* in_sizes, int n_in,
                              void* d_out, int out_size, void* d_ws, size_t ws_size,
                              hipStream_t stream) {
  const float* node_ctx  = (const float*)d_in[0];
  const float* cell_ctx  = (const float*)d_in[1];
  const float* orig      = (const float*)d_in[2];
  const int*   high_mask = (const int*)d_in[3];
  const int*   low_mask  = (const int*)d_in[4];
  const float* init_w    = (const float*)d_in[5];
  const float* Wc        = (const float*)d_in[6];
  const float* bc        = (const float*)d_in[7];
  const float* Wv        = (const float*)d_in[8];
  const float* bv        = (const float*)d_in[9];
  const float* hWq       = (const float*)d_in[10];
  const float* hbq       = (const float*)d_in[11];
  const float* hWr       = (const float*)d_in[12];
  const float* hbr       = (const float*)d_in[13];
  const float* hv        = (const float*)d_in[14];
  const float* low_init_w= (const float*)d_in[15];
  const float* lWc       = (const float*)d_in[16];
  const float* lbc       = (const float*)d_in[17];
  const float* lWv       = (const float*)d_in[18];
  const float* lbv       = (const float*)d_in[19];
  const float* lWq       = (const float*)d_in[20];
  const float* lbq       = (const float*)d_in[21];
  const float* lWr       = (const float*)d_in[22];
  const float* lbr       = (const float*)d_in[23];
  const float* lv        = (const float*)d_in[24];
  float* out = (float*)d_out;

  char* ws = (char*)d_ws;
  size_t off = 0;
  auto alloc = [&](size_t bytes) -> void* {
    void* p = ws + off;
    off += (bytes + 255) & ~(size_t)255;
    return p;
  };
  unsigned* w_hkeys = (unsigned*)alloc(32*2*4);
  unsigned* w_lkeys = (unsigned*)alloc(32*2*4);
  int*   w_hidx  = (int*)alloc(2048*4);
  int*   w_arow  = (int*)alloc(2048*4);
  int*   w_cell  = (int*)alloc(2048*4);
  float* w_hlogp = (float*)alloc(64*4);
  float* w_llogp = (float*)alloc(2048*4);
  float* w_lR    = (float*)alloc(2048*4);
  float* w_lastn = (float*)alloc(2048*2*4);
  float* w_initn = (float*)alloc(2048*2*4);
  float* w_g0h   = (float*)alloc(256*4);
  float* w_g0l   = (float*)alloc(256*4);
  float* w_Lsum  = (float*)alloc(4);
  float* w_M1h   = (float*)alloc((size_t)65536*4);
  float* w_Ah    = (float*)alloc((size_t)65536*4);
  float* w_M1l   = (float*)alloc((size_t)65536*4);
  float* w_Al    = (float*)alloc((size_t)65536*4);
  float* w_mcc   = (float*)alloc((size_t)64*256*4);
  float* w_mnc   = (float*)alloc((size_t)2048*256*4);
  float* w_hbh   = (float*)alloc((size_t)64*256*4);
  float* w_hq0h  = (float*)alloc((size_t)64*256*4);
  float* w_rhigh = (float*)alloc((size_t)2048*256*4);
  float* w_Qh    = (float*)alloc((size_t)2048*256*4);
  float* w_hbl   = (float*)alloc((size_t)2048*256*4);
  float* w_hq0l  = (float*)alloc((size_t)2048*256*4);
  float* w_u0    = (float*)alloc((size_t)2048*64*4);
  float* w_sbase = (float*)alloc((size_t)2048*256*4);
  float* w_U     = (float*)alloc((size_t)2048*4096*4);
  float* w_R     = (float*)alloc((size_t)2048*64*256*4);
  float* w_Qm    = (float*)alloc((size_t)2048*64*256*4);
  (void)ws_size; (void)in_sizes; (void)n_in; (void)out_size;

  k0_kernel<<<1, 256, 0, stream>>>(init_w, Wv, hWq, low_init_w, lWv, lWq, lv,
                                   w_hkeys, w_lkeys, w_g0h, w_g0l, w_Lsum);
  k_mean<<<2048, 256, 0, stream>>>(node_ctx, w_mnc, 64);
  k_mean<<<64, 256, 0, stream>>>(cell_ctx, w_mcc, 32);

  dim3 g256(16, 4), g2048(128, 4), g64(4, 4);
  k_gemm<<<g256, 256, 0, stream>>>(Wv,            256, nullptr, hWq, nullptr, w_M1h, 256, 256, 256);
  k_gemm<<<g256, 256, 0, stream>>>(Wv + 65536,    256, nullptr, hWq, nullptr, w_Ah,  256, 256, 256);
  k_gemm<<<g256, 256, 0, stream>>>(lWv,           256, nullptr, lWq, nullptr, w_M1l, 256, 256, 256);
  k_gemm<<<g256, 256, 0, stream>>>(lWv + 65536,   256, nullptr, lWq, nullptr, w_Al,  256, 256, 256);
  k_gemm<<<g2048, 256, 0, stream>>>(cell_ctx, 256, nullptr, hWr, hbr, w_rhigh, 2048, 256, 256);
  k_gemm<<<g2048, 256, 0, stream>>>(cell_ctx, 256, nullptr, w_Ah, nullptr, w_Qh, 2048, 256, 256);
  k_gemm<<<g64,   256, 0, stream>>>(w_mcc, 256, nullptr, Wc,  bc,  w_hbh, 64,   256, 256);
  k_gemm<<<g2048, 256, 0, stream>>>(w_mnc, 256, nullptr, lWc, lbc, w_hbl, 2048, 256, 256);
  k_gemm<<<g64,   256, 0, stream>>>(w_hbh, 256, bv,  hWq, hbq, w_hq0h, 64,   256, 256);
  k_gemm<<<g2048, 256, 0, stream>>>(w_hbl, 256, lbv, lWq, lbq, w_hq0l, 2048, 256, 256);

  k_bgemm<<<dim3(1024, 4), 256, 0, stream>>>(node_ctx, lWr, w_Al, lbr, w_R, w_Qm);
  k_u0k<<<2048, 256, 0, stream>>>(w_R, w_hq0l, w_g0l, lv, w_u0);

  k_high<<<64, 256, 0, stream>>>(cell_ctx, high_mask, hv, w_hq0h, w_g0h, w_Qh,
                                 w_rhigh, w_M1h, w_hkeys, w_hidx, w_hlogp);
  k_idx0<<<512, 256, 0, stream>>>(low_mask, w_lkeys, w_hidx, w_u0, w_arow, w_cell);
  k_gemmg<<<dim3(128, 4), 256, 0, stream>>>(node_ctx, w_arow, w_cell, w_M1l,
                                            w_hq0l, w_sbase);
  k_utab<<<2048, 512, 0, stream>>>(w_R, w_Qm, w_sbase, lv, w_Lsum, w_hidx, w_U);
  k_lowseq<<<512, 256, 0, stream>>>(orig, low_mask, w_lkeys, w_hidx, w_u0, w_U,
                                    w_llogp, w_lR, w_lastn, w_initn);
  k_stitch<<<1, 64, 0, stream>>>(w_hlogp, w_llogp, w_lR, w_lastn, w_initn, out);
}